// Round 1
// baseline (321.765 us; speedup 1.0000x reference)
//
#include <hip/hip_runtime.h>
#include <hip/hip_bf16.h>
#include <stdint.h>

#define LSEQ 2048
#define NBATCH 2
#define NHEADS 16
#define HDIM 64
#define EMB 1024

typedef __bf16 bf16x8 __attribute__((ext_vector_type(8)));
typedef float f32x4 __attribute__((ext_vector_type(4)));
typedef unsigned short ushort4v __attribute__((ext_vector_type(4)));
typedef unsigned short ushort8v __attribute__((ext_vector_type(8)));

static __device__ __forceinline__ unsigned short f2bf(float f) {
  union { float f; uint32_t u; } v; v.f = f;
  uint32_t u = v.u;
  u += 0x7fffu + ((u >> 16) & 1u);   // RNE
  return (unsigned short)(u >> 16);
}

static __device__ __forceinline__ f32x4 mfma16(bf16x8 a, bf16x8 b, f32x4 c) {
  return __builtin_amdgcn_mfma_f32_16x16x32_bf16(a, b, c, 0, 0, 0);
}

// ---- Q,K: f32 [n][l][h*64+d] -> bf16 [n][h][l][d] ------------------------
__global__ __launch_bounds__(256) void convert_qk_kernel(
    const float* __restrict__ q, const float* __restrict__ k,
    unsigned short* __restrict__ qb, unsigned short* __restrict__ kb) {
  int idx = blockIdx.x * 256 + threadIdx.x;          // 2 * 2^20 float4 granules
  const float* src; unsigned short* dst; int t;
  if (idx < (1 << 20)) { src = q; dst = qb; t = idx; }
  else                 { src = k; dst = kb; t = idx - (1 << 20); }
  int e = t << 2;
  int d = e & 63;
  int h = (e >> 6) & 15;
  int l = (e >> 10) & (LSEQ - 1);
  int n = e >> 21;
  float4 v = reinterpret_cast<const float4*>(src)[t];
  ushort4v o;
  o.x = f2bf(v.x); o.y = f2bf(v.y); o.z = f2bf(v.z); o.w = f2bf(v.w);
  size_t oi = (((size_t)n * NHEADS + h) * LSEQ + l) * HDIM + d;
  *reinterpret_cast<ushort4v*>(dst + oi) = o;
}

// ---- V: f32 [n][l][h*64+d] -> bf16 VT chunks [n][h][kc][d][kp32] ---------
__global__ __launch_bounds__(256) void convert_vt_kernel(
    const float* __restrict__ v, unsigned short* __restrict__ vt) {
  int bid = blockIdx.x;            // n*16*64 + h*64 + kc
  int kc = bid & 63;
  int h  = (bid >> 6) & 15;
  int n  = bid >> 10;
  int t  = threadIdx.x;
  int d   = t >> 2;                // 0..63
  int kp0 = (t & 3) << 3;          // 0,8,16,24
  const float* src = v + (size_t)n * LSEQ * EMB + h * HDIM + d;
  ushort8v o;
#pragma unroll
  for (int j = 0; j < 8; ++j) {
    float f = src[(size_t)(kc * 32 + kp0 + j) * EMB];
    o[j] = f2bf(f);
  }
  size_t base = (((size_t)(n * NHEADS + h) * 64 + kc) * HDIM + d) * 32 + kp0;
  *reinterpret_cast<ushort8v*>(vt + base) = o;
}

// ---- Wo: f32 -> bf16, same [n_out][k] layout -----------------------------
__global__ __launch_bounds__(256) void convert_wo_kernel(
    const float* __restrict__ w, unsigned short* __restrict__ wb) {
  int t = blockIdx.x * 256 + threadIdx.x;            // 2^18 float4 granules
  float4 v = reinterpret_cast<const float4*>(w)[t];
  ushort4v o;
  o.x = f2bf(v.x); o.y = f2bf(v.y); o.z = f2bf(v.z); o.w = f2bf(v.w);
  reinterpret_cast<ushort4v*>(wb)[t] = o;
}

// ---- Flash attention: no LDS, all fragments direct 16B global loads ------
// Swapped QK^T: D1 = K_tile(16kp x 32d) * Q^T(32d x 16q) -> e[kp][q]
// PV (out^T):  D2 = VT_sub(16d x 32kp) * P(32kp x 16q)  -> o[d][q]
// Fixed-max softmax: p = mask ? exp2(e*c - 96c) : 0   (c = log2e/32)
__global__ __launch_bounds__(256) void attn_kernel(
    const unsigned short* __restrict__ Qb, const unsigned short* __restrict__ Kb,
    const unsigned short* __restrict__ VT, const int* __restrict__ mask,
    unsigned short* __restrict__ Op) {
  int bid = blockIdx.x;            // n*512 + h*32 + qt
  int qt = bid & 31;
  int h  = (bid >> 5) & 15;
  int n  = bid >> 9;
  int wave = threadIdx.x >> 6;
  int lane = threadIdx.x & 63;
  int g  = lane >> 4;              // lane group 0..3
  int qi = lane & 15;
  int qrow = qt * 64 + wave * 16 + qi;

  const unsigned short* qptr = Qb + (((size_t)n * NHEADS + h) * LSEQ + qrow) * HDIM;
  bf16x8 bq0 = *reinterpret_cast<const bf16x8*>(qptr + g * 8);        // d 0..31
  bf16x8 bq1 = *reinterpret_cast<const bf16x8*>(qptr + 32 + g * 8);   // d 32..63

  const unsigned short* kbase  = Kb + (((size_t)n * NHEADS + h) * LSEQ) * HDIM;
  const unsigned short* vtbase = VT + ((size_t)(n * NHEADS + h) * 64) * (HDIM * 32);
  const int* mrow = mask + ((size_t)n * LSEQ + qrow) * LSEQ;

  f32x4 z = {0.f, 0.f, 0.f, 0.f};
  f32x4 acc0 = z, acc1 = z, acc2 = z, acc3 = z;
  float ssum = 0.f;
  const float c  = 1.44269504088896f / 32.0f;
  const float mc = 96.0f * c;

  for (int kc = 0; kc < 64; ++kc) {
    const unsigned short* kr = kbase + (size_t)(kc * 32) * HDIM;
    f32x4 e0 = z, e1 = z;
    bf16x8 a;
    a = *(const bf16x8*)(kr + qi * HDIM + g * 8);             e0 = mfma16(a, bq0, e0);
    a = *(const bf16x8*)(kr + qi * HDIM + 32 + g * 8);        e0 = mfma16(a, bq1, e0);
    a = *(const bf16x8*)(kr + (16 + qi) * HDIM + g * 8);      e1 = mfma16(a, bq0, e1);
    a = *(const bf16x8*)(kr + (16 + qi) * HDIM + 32 + g * 8); e1 = mfma16(a, bq1, e1);

    int4 m0 = *reinterpret_cast<const int4*>(mrow + kc * 32 + 4 * g);
    int4 m1 = *reinterpret_cast<const int4*>(mrow + kc * 32 + 16 + 4 * g);

    float p0 = m0.x ? exp2f(e0[0] * c - mc) : 0.f;
    float p1 = m0.y ? exp2f(e0[1] * c - mc) : 0.f;
    float p2 = m0.z ? exp2f(e0[2] * c - mc) : 0.f;
    float p3 = m0.w ? exp2f(e0[3] * c - mc) : 0.f;
    float p4 = m1.x ? exp2f(e1[0] * c - mc) : 0.f;
    float p5 = m1.y ? exp2f(e1[1] * c - mc) : 0.f;
    float p6 = m1.z ? exp2f(e1[2] * c - mc) : 0.f;
    float p7 = m1.w ? exp2f(e1[3] * c - mc) : 0.f;
    ssum += ((p0 + p1) + (p2 + p3)) + ((p4 + p5) + (p6 + p7));

    uint32_t pk00 = (uint32_t)f2bf(p0) | ((uint32_t)f2bf(p1) << 16);
    uint32_t pk01 = (uint32_t)f2bf(p2) | ((uint32_t)f2bf(p3) << 16);
    uint32_t pk10 = (uint32_t)f2bf(p4) | ((uint32_t)f2bf(p5) << 16);
    uint32_t pk11 = (uint32_t)f2bf(p6) | ((uint32_t)f2bf(p7) << 16);

    // Relayout e-tile P (kp = 16t+4g'+r) -> PV B-frag (kp = 8g+j)
    int srcA = ((g & 1) << 5) + qi;      // s0 = (g&1)*2 -> lane s0*16+qi
    int srcB = srcA + 16;
    uint32_t a0 = (uint32_t)__shfl((int)pk00, srcA, 64);
    uint32_t a1 = (uint32_t)__shfl((int)pk01, srcA, 64);
    uint32_t a2 = (uint32_t)__shfl((int)pk10, srcA, 64);
    uint32_t a3 = (uint32_t)__shfl((int)pk11, srcA, 64);
    uint32_t b0 = (uint32_t)__shfl((int)pk00, srcB, 64);
    uint32_t b1 = (uint32_t)__shfl((int)pk01, srcB, 64);
    uint32_t b2 = (uint32_t)__shfl((int)pk10, srcB, 64);
    uint32_t b3 = (uint32_t)__shfl((int)pk11, srcB, 64);
    bool th = g >= 2;                    // tile t = g>>1
    union { uint32_t u[4]; bf16x8 v; } pf;
    pf.u[0] = th ? a2 : a0;
    pf.u[1] = th ? a3 : a1;
    pf.u[2] = th ? b2 : b0;
    pf.u[3] = th ? b3 : b1;

    const unsigned short* vc = vtbase + (size_t)kc * (HDIM * 32);
    bf16x8 av;
    av = *(const bf16x8*)(vc + qi * 32 + g * 8);        acc0 = mfma16(av, pf.v, acc0);
    av = *(const bf16x8*)(vc + (16 + qi) * 32 + g * 8); acc1 = mfma16(av, pf.v, acc1);
    av = *(const bf16x8*)(vc + (32 + qi) * 32 + g * 8); acc2 = mfma16(av, pf.v, acc2);
    av = *(const bf16x8*)(vc + (48 + qi) * 32 + g * 8); acc3 = mfma16(av, pf.v, acc3);
  }

  ssum += __shfl_xor(ssum, 16, 64);
  ssum += __shfl_xor(ssum, 32, 64);
  float inv = 1.0f / ssum;

  // acc holds out^T[d][q]: lane q = qi, d = dsub*16 + 4g + r
  size_t ob = ((size_t)n * LSEQ + qrow) * EMB + h * HDIM;
  ushort4v s0, s1, s2, s3;
#pragma unroll
  for (int r = 0; r < 4; ++r) {
    s0[r] = f2bf(acc0[r] * inv);
    s1[r] = f2bf(acc1[r] * inv);
    s2[r] = f2bf(acc2[r] * inv);
    s3[r] = f2bf(acc3[r] * inv);
  }
  *reinterpret_cast<ushort4v*>(Op + ob + 0  + 4 * g) = s0;
  *reinterpret_cast<ushort4v*>(Op + ob + 16 + 4 * g) = s1;
  *reinterpret_cast<ushort4v*>(Op + ob + 32 + 4 * g) = s2;
  *reinterpret_cast<ushort4v*>(Op + ob + 48 + 4 * g) = s3;
}

// ---- Projection: out[m][j] = sum_k Op[m][k] * Wo[j][k] + bo[j] (fp32 out)
__global__ __launch_bounds__(256) void proj_kernel(
    const unsigned short* __restrict__ A, const unsigned short* __restrict__ B,
    const float* __restrict__ bo, float* __restrict__ out) {
  int bid = blockIdx.x;
  int mb = bid & 63;
  int nb = bid >> 6;
  int wave = threadIdx.x >> 6;
  int lane = threadIdx.x & 63;
  int g = lane >> 4, qi = lane & 15;
  const unsigned short* ap  = A + (size_t)(mb * 64 + wave * 16 + qi) * EMB;
  const unsigned short* bp  = B + (size_t)(nb * 64 + qi) * EMB;
  f32x4 z = {0.f, 0.f, 0.f, 0.f};
  f32x4 acc0 = z, acc1 = z, acc2 = z, acc3 = z;
  for (int kt = 0; kt < 32; ++kt) {
    bf16x8 a  = *(const bf16x8*)(ap + kt * 32 + g * 8);
    bf16x8 b0 = *(const bf16x8*)(bp + kt * 32 + g * 8);
    bf16x8 b1 = *(const bf16x8*)(bp + 16 * EMB + kt * 32 + g * 8);
    bf16x8 b2 = *(const bf16x8*)(bp + 32 * EMB + kt * 32 + g * 8);
    bf16x8 b3 = *(const bf16x8*)(bp + 48 * EMB + kt * 32 + g * 8);
    acc0 = mfma16(a, b0, acc0);
    acc1 = mfma16(a, b1, acc1);
    acc2 = mfma16(a, b2, acc2);
    acc3 = mfma16(a, b3, acc3);
  }
  int mrow = mb * 64 + wave * 16 + 4 * g;
#pragma unroll
  for (int r = 0; r < 4; ++r) {
    int row = mrow + r;
    int c0 = nb * 64 + qi;
    out[(size_t)row * EMB + c0]      = acc0[r] + bo[c0];
    out[(size_t)row * EMB + c0 + 16] = acc1[r] + bo[c0 + 16];
    out[(size_t)row * EMB + c0 + 32] = acc2[r] + bo[c0 + 32];
    out[(size_t)row * EMB + c0 + 48] = acc3[r] + bo[c0 + 48];
  }
}

extern "C" void kernel_launch(void* const* d_in, const int* in_sizes, int n_in,
                              void* d_out, int out_size, void* d_ws, size_t ws_size,
                              hipStream_t stream) {
  const float* Vf   = (const float*)d_in[0];
  const float* Kf   = (const float*)d_in[1];
  const float* Qf   = (const float*)d_in[2];
  const int*   Mask = (const int*)d_in[3];
  const float* Wo   = (const float*)d_in[4];
  const float* Bo   = (const float*)d_in[5];
  float* out = (float*)d_out;

  char* ws = (char*)d_ws;
  // ws layout (bytes): Qb 8MB | Kb 8MB | VT 8MB | Wob 2MB | Op 8MB  = 34MB
  unsigned short* Qb  = (unsigned short*)(ws);
  unsigned short* Kb  = (unsigned short*)(ws + (size_t)8  * 1024 * 1024);
  unsigned short* VTb = (unsigned short*)(ws + (size_t)16 * 1024 * 1024);
  unsigned short* Wob = (unsigned short*)(ws + (size_t)24 * 1024 * 1024);
  unsigned short* Opb = (unsigned short*)(ws + (size_t)26 * 1024 * 1024);

  convert_qk_kernel<<<8192, 256, 0, stream>>>(Qf, Kf, Qb, Kb);
  convert_vt_kernel<<<2048, 256, 0, stream>>>(Vf, VTb);
  convert_wo_kernel<<<1024, 256, 0, stream>>>(Wo, Wob);
  attn_kernel<<<1024, 256, 0, stream>>>(Qb, Kb, VTb, Mask, Opb);
  proj_kernel<<<1024, 256, 0, stream>>>(Opb, Wob, Bo, out);
}

// Round 2
// 307.471 us; speedup vs baseline: 1.0465x; 1.0465x over previous
//
#include <hip/hip_runtime.h>
#include <hip/hip_bf16.h>
#include <stdint.h>

#define LSEQ 2048
#define NBATCH 2
#define NHEADS 16
#define HDIM 64
#define EMB 1024

typedef __bf16 bf16x8 __attribute__((ext_vector_type(8)));
typedef float f32x4 __attribute__((ext_vector_type(4)));
typedef unsigned short ushort4v __attribute__((ext_vector_type(4)));
typedef unsigned short ushort8v __attribute__((ext_vector_type(8)));

static __device__ __forceinline__ unsigned short f2bf(float f) {
  union { float f; uint32_t u; } v; v.f = f;
  uint32_t u = v.u;
  u += 0x7fffu + ((u >> 16) & 1u);   // RNE
  return (unsigned short)(u >> 16);
}

static __device__ __forceinline__ f32x4 mfma16(bf16x8 a, bf16x8 b, f32x4 c) {
  return __builtin_amdgcn_mfma_f32_16x16x32_bf16(a, b, c, 0, 0, 0);
}

// ---- Q,K: f32 [n][l][h*64+d] -> bf16 [n][h][l][d] ------------------------
__global__ __launch_bounds__(256) void convert_qk_kernel(
    const float* __restrict__ q, const float* __restrict__ k,
    unsigned short* __restrict__ qb, unsigned short* __restrict__ kb) {
  int idx = blockIdx.x * 256 + threadIdx.x;          // 2 * 2^20 float4 granules
  const float* src; unsigned short* dst; int t;
  if (idx < (1 << 20)) { src = q; dst = qb; t = idx; }
  else                 { src = k; dst = kb; t = idx - (1 << 20); }
  int e = t << 2;
  int d = e & 63;
  int h = (e >> 6) & 15;
  int l = (e >> 10) & (LSEQ - 1);
  int n = e >> 21;
  float4 v = reinterpret_cast<const float4*>(src)[t];
  ushort4v o;
  o.x = f2bf(v.x); o.y = f2bf(v.y); o.z = f2bf(v.z); o.w = f2bf(v.w);
  size_t oi = (((size_t)n * NHEADS + h) * LSEQ + l) * HDIM + d;
  *reinterpret_cast<ushort4v*>(dst + oi) = o;
}

// ---- V: f32 [n][l][h*64+d] -> bf16 VT chunks [n][h][kc][d][kp32] ---------
__global__ __launch_bounds__(256) void convert_vt_kernel(
    const float* __restrict__ v, unsigned short* __restrict__ vt) {
  int bid = blockIdx.x;            // n*16*64 + h*64 + kc
  int kc = bid & 63;
  int h  = (bid >> 6) & 15;
  int n  = bid >> 10;
  int t  = threadIdx.x;
  int d   = t & 63;                // consecutive lanes -> consecutive d: coalesced reads
  int kp0 = (t >> 6) << 3;         // 0,8,16,24
  const float* src = v + (size_t)n * LSEQ * EMB + h * HDIM + d;
  ushort8v o;
#pragma unroll
  for (int j = 0; j < 8; ++j) {
    float f = src[(size_t)(kc * 32 + kp0 + j) * EMB];
    o[j] = f2bf(f);
  }
  size_t base = (((size_t)(n * NHEADS + h) * 64 + kc) * HDIM + d) * 32 + kp0;
  *reinterpret_cast<ushort8v*>(vt + base) = o;
}

// ---- Wo: f32 -> bf16, same [n_out][k] layout -----------------------------
__global__ __launch_bounds__(256) void convert_wo_kernel(
    const float* __restrict__ w, unsigned short* __restrict__ wb) {
  int t = blockIdx.x * 256 + threadIdx.x;            // 2^18 float4 granules
  float4 v = reinterpret_cast<const float4*>(w)[t];
  ushort4v o;
  o.x = f2bf(v.x); o.y = f2bf(v.y); o.z = f2bf(v.z); o.w = f2bf(v.w);
  reinterpret_cast<ushort4v*>(wb)[t] = o;
}

// ---- mask int32 [n][1][L][L] -> bitmask (1 bit per entry, same linear order)
__global__ __launch_bounds__(256) void mask_bits_kernel(
    const int* __restrict__ mask, unsigned long long* __restrict__ mb) {
  int idx = blockIdx.x * 256 + threadIdx.x;
  int v = mask[idx];
  unsigned long long b = __ballot(v != 0);
  if ((threadIdx.x & 63) == 0) mb[idx >> 6] = b;
}

// ---- Flash attention: no LDS, double-buffered register prefetch ----------
// Swapped QK^T: D1 = K_tile(16kp x 32d) * Q^T(32d x 16q) -> e[kp][q]
// PV (out^T):  D2 = VT_sub(16d x 32kp) * P(32kp x 16q)  -> o[d][q]
// Fixed-max softmax: p = maskbit ? exp2(e*c - 96c) : 0   (c = log2e/32)
__global__ __launch_bounds__(256, 4) void attn_kernel(
    const unsigned short* __restrict__ Qb, const unsigned short* __restrict__ Kb,
    const unsigned short* __restrict__ VT, const uint32_t* __restrict__ maskw,
    unsigned short* __restrict__ Op) {
  int bid = blockIdx.x;
  bid = (bid & 7) * 128 + (bid >> 3);  // XCD swizzle: 128-block chunks per XCD
  int qt = bid & 31;
  int h  = (bid >> 5) & 15;
  int n  = bid >> 9;
  int wave = threadIdx.x >> 6;
  int lane = threadIdx.x & 63;
  int g  = lane >> 4;              // lane group 0..3
  int qi = lane & 15;
  int qrow = qt * 64 + wave * 16 + qi;

  const unsigned short* qptr = Qb + (((size_t)n * NHEADS + h) * LSEQ + qrow) * HDIM;
  bf16x8 bq0 = *reinterpret_cast<const bf16x8*>(qptr + g * 8);        // d 0..31
  bf16x8 bq1 = *reinterpret_cast<const bf16x8*>(qptr + 32 + g * 8);   // d 32..63

  const unsigned short* kbase  = Kb + (((size_t)n * NHEADS + h) * LSEQ) * HDIM;
  const unsigned short* vtbase = VT + ((size_t)(n * NHEADS + h) * 64) * (HDIM * 32);
  const uint32_t* mrow = maskw + ((size_t)n * LSEQ + qrow) * 64;

  f32x4 z = {0.f, 0.f, 0.f, 0.f};
  f32x4 acc0 = z, acc1 = z, acc2 = z, acc3 = z;
  float ssum = 0.f;
  const float c  = 1.44269504088896f / 32.0f;
  const float mc = 96.0f * c;

#define LOADS(KC, K0,K1,K2,K3,V0,V1,V2,V3,MW) do {                      \
    const unsigned short* kr_ = kbase + (size_t)((KC) * 32) * HDIM;     \
    K0 = *(const bf16x8*)(kr_ + qi * HDIM + g * 8);                     \
    K1 = *(const bf16x8*)(kr_ + qi * HDIM + 32 + g * 8);                \
    K2 = *(const bf16x8*)(kr_ + (16 + qi) * HDIM + g * 8);              \
    K3 = *(const bf16x8*)(kr_ + (16 + qi) * HDIM + 32 + g * 8);         \
    const unsigned short* vc_ = vtbase + (size_t)(KC) * (HDIM * 32);    \
    V0 = *(const bf16x8*)(vc_ + qi * 32 + g * 8);                       \
    V1 = *(const bf16x8*)(vc_ + (16 + qi) * 32 + g * 8);                \
    V2 = *(const bf16x8*)(vc_ + (32 + qi) * 32 + g * 8);                \
    V3 = *(const bf16x8*)(vc_ + (48 + qi) * 32 + g * 8);                \
    MW = mrow[(KC)];                                                    \
  } while (0)

#define COMPUTE(K0,K1,K2,K3,V0,V1,V2,V3,MW) do {                        \
    f32x4 e0 = z, e1 = z;                                               \
    e0 = mfma16(K0, bq0, e0); e0 = mfma16(K1, bq1, e0);                 \
    e1 = mfma16(K2, bq0, e1); e1 = mfma16(K3, bq1, e1);                 \
    uint32_t m0_ = (MW) >> (4 * g);                                     \
    uint32_t m1_ = (MW) >> (16 + 4 * g);                                \
    float p0 = (m0_ & 1u) ? __builtin_amdgcn_exp2f(e0[0] * c - mc) : 0.f; \
    float p1 = (m0_ & 2u) ? __builtin_amdgcn_exp2f(e0[1] * c - mc) : 0.f; \
    float p2 = (m0_ & 4u) ? __builtin_amdgcn_exp2f(e0[2] * c - mc) : 0.f; \
    float p3 = (m0_ & 8u) ? __builtin_amdgcn_exp2f(e0[3] * c - mc) : 0.f; \
    float p4 = (m1_ & 1u) ? __builtin_amdgcn_exp2f(e1[0] * c - mc) : 0.f; \
    float p5 = (m1_ & 2u) ? __builtin_amdgcn_exp2f(e1[1] * c - mc) : 0.f; \
    float p6 = (m1_ & 4u) ? __builtin_amdgcn_exp2f(e1[2] * c - mc) : 0.f; \
    float p7 = (m1_ & 8u) ? __builtin_amdgcn_exp2f(e1[3] * c - mc) : 0.f; \
    ssum += ((p0 + p1) + (p2 + p3)) + ((p4 + p5) + (p6 + p7));          \
    uint32_t pk00, pk01, pk10, pk11;                                    \
    asm("v_cvt_pk_bf16_f32 %0, %1, %2" : "=v"(pk00) : "v"(p0), "v"(p1)); \
    asm("v_cvt_pk_bf16_f32 %0, %1, %2" : "=v"(pk01) : "v"(p2), "v"(p3)); \
    asm("v_cvt_pk_bf16_f32 %0, %1, %2" : "=v"(pk10) : "v"(p4), "v"(p5)); \
    asm("v_cvt_pk_bf16_f32 %0, %1, %2" : "=v"(pk11) : "v"(p6), "v"(p7)); \
    int srcA = ((g & 1) << 5) + qi;                                     \
    int srcB = srcA + 16;                                               \
    uint32_t a0 = (uint32_t)__shfl((int)pk00, srcA, 64);                \
    uint32_t a1 = (uint32_t)__shfl((int)pk01, srcA, 64);                \
    uint32_t a2 = (uint32_t)__shfl((int)pk10, srcA, 64);                \
    uint32_t a3 = (uint32_t)__shfl((int)pk11, srcA, 64);                \
    uint32_t b0 = (uint32_t)__shfl((int)pk00, srcB, 64);                \
    uint32_t b1 = (uint32_t)__shfl((int)pk01, srcB, 64);                \
    uint32_t b2 = (uint32_t)__shfl((int)pk10, srcB, 64);                \
    uint32_t b3 = (uint32_t)__shfl((int)pk11, srcB, 64);                \
    bool th = g >= 2;                                                   \
    union { uint32_t u[4]; bf16x8 v; } pf;                              \
    pf.u[0] = th ? a2 : a0;                                             \
    pf.u[1] = th ? a3 : a1;                                             \
    pf.u[2] = th ? b2 : b0;                                             \
    pf.u[3] = th ? b3 : b1;                                             \
    acc0 = mfma16(V0, pf.v, acc0);                                      \
    acc1 = mfma16(V1, pf.v, acc1);                                      \
    acc2 = mfma16(V2, pf.v, acc2);                                      \
    acc3 = mfma16(V3, pf.v, acc3);                                      \
  } while (0)

  bf16x8 k0a, k1a, k2a, k3a, v0a, v1a, v2a, v3a; uint32_t ma;
  bf16x8 k0b, k1b, k2b, k3b, v0b, v1b, v2b, v3b; uint32_t mbw;

  LOADS(0, k0a, k1a, k2a, k3a, v0a, v1a, v2a, v3a, ma);
  for (int kc = 0; kc < 64; kc += 2) {
    LOADS(kc + 1, k0b, k1b, k2b, k3b, v0b, v1b, v2b, v3b, mbw);
    COMPUTE(k0a, k1a, k2a, k3a, v0a, v1a, v2a, v3a, ma);
    int kc2 = (kc + 2 < 64) ? kc + 2 : 0;     // clamp keeps loads in-bounds
    LOADS(kc2, k0a, k1a, k2a, k3a, v0a, v1a, v2a, v3a, ma);
    COMPUTE(k0b, k1b, k2b, k3b, v0b, v1b, v2b, v3b, mbw);
  }
#undef LOADS
#undef COMPUTE

  ssum += __shfl_xor(ssum, 16, 64);
  ssum += __shfl_xor(ssum, 32, 64);
  float inv = 1.0f / ssum;

  // acc holds out^T[d][q]: lane q = qi, d = dsub*16 + 4g + r
  size_t ob = ((size_t)n * LSEQ + qrow) * EMB + h * HDIM;
  ushort4v s0, s1, s2, s3;
#pragma unroll
  for (int r = 0; r < 4; ++r) {
    s0[r] = f2bf(acc0[r] * inv);
    s1[r] = f2bf(acc1[r] * inv);
    s2[r] = f2bf(acc2[r] * inv);
    s3[r] = f2bf(acc3[r] * inv);
  }
  *reinterpret_cast<ushort4v*>(Op + ob + 0  + 4 * g) = s0;
  *reinterpret_cast<ushort4v*>(Op + ob + 16 + 4 * g) = s1;
  *reinterpret_cast<ushort4v*>(Op + ob + 32 + 4 * g) = s2;
  *reinterpret_cast<ushort4v*>(Op + ob + 48 + 4 * g) = s3;
}

// ---- Projection: out[m][j] = sum_k Op[m][k] * Wo[j][k] + bo[j] (fp32 out)
__global__ __launch_bounds__(256) void proj_kernel(
    const unsigned short* __restrict__ A, const unsigned short* __restrict__ B,
    const float* __restrict__ bo, float* __restrict__ out) {
  int bid = blockIdx.x;
  int mb = bid & 63;
  int nb = bid >> 6;
  int wave = threadIdx.x >> 6;
  int lane = threadIdx.x & 63;
  int g = lane >> 4, qi = lane & 15;
  const unsigned short* ap  = A + (size_t)(mb * 64 + wave * 16 + qi) * EMB;
  const unsigned short* bp  = B + (size_t)(nb * 64 + qi) * EMB;
  f32x4 z = {0.f, 0.f, 0.f, 0.f};
  f32x4 acc0 = z, acc1 = z, acc2 = z, acc3 = z;
  for (int kt = 0; kt < 32; ++kt) {
    bf16x8 a  = *(const bf16x8*)(ap + kt * 32 + g * 8);
    bf16x8 b0 = *(const bf16x8*)(bp + kt * 32 + g * 8);
    bf16x8 b1 = *(const bf16x8*)(bp + 16 * EMB + kt * 32 + g * 8);
    bf16x8 b2 = *(const bf16x8*)(bp + 32 * EMB + kt * 32 + g * 8);
    bf16x8 b3 = *(const bf16x8*)(bp + 48 * EMB + kt * 32 + g * 8);
    acc0 = mfma16(a, b0, acc0);
    acc1 = mfma16(a, b1, acc1);
    acc2 = mfma16(a, b2, acc2);
    acc3 = mfma16(a, b3, acc3);
  }
  int mrow = mb * 64 + wave * 16 + 4 * g;
#pragma unroll
  for (int r = 0; r < 4; ++r) {
    int row = mrow + r;
    int c0 = nb * 64 + qi;
    out[(size_t)row * EMB + c0]      = acc0[r] + bo[c0];
    out[(size_t)row * EMB + c0 + 16] = acc1[r] + bo[c0 + 16];
    out[(size_t)row * EMB + c0 + 32] = acc2[r] + bo[c0 + 32];
    out[(size_t)row * EMB + c0 + 48] = acc3[r] + bo[c0 + 48];
  }
}

extern "C" void kernel_launch(void* const* d_in, const int* in_sizes, int n_in,
                              void* d_out, int out_size, void* d_ws, size_t ws_size,
                              hipStream_t stream) {
  const float* Vf   = (const float*)d_in[0];
  const float* Kf   = (const float*)d_in[1];
  const float* Qf   = (const float*)d_in[2];
  const int*   Mask = (const int*)d_in[3];
  const float* Wo   = (const float*)d_in[4];
  const float* Bo   = (const float*)d_in[5];
  float* out = (float*)d_out;

  char* ws = (char*)d_ws;
  // ws layout (bytes): Qb 8MB | Kb 8MB | VT 8MB | Wob 2MB | Opb 8MB | Mb 1MB
  unsigned short* Qb  = (unsigned short*)(ws);
  unsigned short* Kb  = (unsigned short*)(ws + (size_t)8  * 1024 * 1024);
  unsigned short* VTb = (unsigned short*)(ws + (size_t)16 * 1024 * 1024);
  unsigned short* Wob = (unsigned short*)(ws + (size_t)24 * 1024 * 1024);
  unsigned short* Opb = (unsigned short*)(ws + (size_t)26 * 1024 * 1024);
  unsigned long long* Mb = (unsigned long long*)(ws + (size_t)34 * 1024 * 1024);

  convert_qk_kernel<<<8192, 256, 0, stream>>>(Qf, Kf, Qb, Kb);
  convert_vt_kernel<<<2048, 256, 0, stream>>>(Vf, VTb);
  convert_wo_kernel<<<1024, 256, 0, stream>>>(Wo, Wob);
  mask_bits_kernel<<<32768, 256, 0, stream>>>(Mask, Mb);
  attn_kernel<<<1024, 256, 0, stream>>>(Qb, Kb, VTb, (const uint32_t*)Mb, Opb);
  proj_kernel<<<1024, 256, 0, stream>>>(Opb, Wob, Bo, out);
}

// Round 3
// 173.827 us; speedup vs baseline: 1.8511x; 1.7688x over previous
//
#include <hip/hip_runtime.h>
#include <hip/hip_bf16.h>
#include <stdint.h>

#define LSEQ 2048
#define NBATCH 2
#define NHEADS 16
#define HDIM 64
#define EMB 1024

typedef __bf16 bf16x8 __attribute__((ext_vector_type(8)));
typedef float f32x4 __attribute__((ext_vector_type(4)));
typedef unsigned short ushort4v __attribute__((ext_vector_type(4)));
typedef unsigned short ushort8v __attribute__((ext_vector_type(8)));

static __device__ __forceinline__ unsigned short f2bf(float f) {
  union { float f; uint32_t u; } v; v.f = f;
  uint32_t u = v.u;
  u += 0x7fffu + ((u >> 16) & 1u);   // RNE
  return (unsigned short)(u >> 16);
}

static __device__ __forceinline__ f32x4 mfma16(bf16x8 a, bf16x8 b, f32x4 c) {
  return __builtin_amdgcn_mfma_f32_16x16x32_bf16(a, b, c, 0, 0, 0);
}

// ---- Q,K: f32 [n][l][h*64+d] -> bf16 [n][h][l][d] ------------------------
// K rows stored with 16B-group swizzle: grp' = grp ^ (l&7)  (bank-conflict-free
// ds_read_b128 after linear global_load_lds staging). Q stays linear.
__global__ __launch_bounds__(256) void convert_qk_kernel(
    const float* __restrict__ q, const float* __restrict__ k,
    unsigned short* __restrict__ qb, unsigned short* __restrict__ kb) {
  int idx = blockIdx.x * 256 + threadIdx.x;          // 2 * 2^20 float4 granules
  const float* src; unsigned short* dst; int t; int swz;
  if (idx < (1 << 20)) { src = q; dst = qb; t = idx; swz = 0; }
  else                 { src = k; dst = kb; t = idx - (1 << 20); swz = 1; }
  int e = t << 2;
  int d = e & 63;
  int h = (e >> 6) & 15;
  int l = (e >> 10) & (LSEQ - 1);
  int n = e >> 21;
  float4 v = reinterpret_cast<const float4*>(src)[t];
  ushort4v o;
  o.x = f2bf(v.x); o.y = f2bf(v.y); o.z = f2bf(v.z); o.w = f2bf(v.w);
  int dd = d;
  if (swz) dd = ((((d >> 3) ^ (l & 7)) << 3) | (d & 7));
  size_t oi = (((size_t)n * NHEADS + h) * LSEQ + l) * HDIM + dd;
  *reinterpret_cast<ushort4v*>(dst + oi) = o;
}

// ---- V: f32 [n][l][h*64+d] -> bf16 VT chunks [n][h][kc][d][kp32] ---------
// 16B-group swizzle within each 64B d-row: c' = c ^ ((d>>1)&3)
__global__ __launch_bounds__(256) void convert_vt_kernel(
    const float* __restrict__ v, unsigned short* __restrict__ vt) {
  int bid = blockIdx.x;            // n*16*64 + h*64 + kc
  int kc = bid & 63;
  int h  = (bid >> 6) & 15;
  int n  = bid >> 10;
  int t  = threadIdx.x;
  int d   = t & 63;                // consecutive lanes -> consecutive d: coalesced
  int kp0 = (t >> 6) << 3;         // 0,8,16,24
  const float* src = v + (size_t)n * LSEQ * EMB + h * HDIM + d;
  ushort8v o;
#pragma unroll
  for (int j = 0; j < 8; ++j) {
    float f = src[(size_t)(kc * 32 + kp0 + j) * EMB];
    o[j] = f2bf(f);
  }
  int c  = kp0 >> 3;
  int cs = c ^ ((d >> 1) & 3);
  size_t base = (((size_t)(n * NHEADS + h) * 64 + kc) * HDIM + d) * 32 + (cs << 3);
  *reinterpret_cast<ushort8v*>(vt + base) = o;
}

// ---- Wo: f32 -> bf16, same [n_out][k] layout -----------------------------
__global__ __launch_bounds__(256) void convert_wo_kernel(
    const float* __restrict__ w, unsigned short* __restrict__ wb) {
  int t = blockIdx.x * 256 + threadIdx.x;            // 2^18 float4 granules
  float4 v = reinterpret_cast<const float4*>(w)[t];
  ushort4v o;
  o.x = f2bf(v.x); o.y = f2bf(v.y); o.z = f2bf(v.z); o.w = f2bf(v.w);
  reinterpret_cast<ushort4v*>(wb)[t] = o;
}

// ---- mask int32 [n][1][L][L] -> bitmask (1 bit per entry) ----------------
__global__ __launch_bounds__(256) void mask_bits_kernel(
    const int* __restrict__ mask, unsigned long long* __restrict__ mb) {
  int idx = blockIdx.x * 256 + threadIdx.x;
  int v = mask[idx];
  unsigned long long b = __ballot(v != 0);
  if ((threadIdx.x & 63) == 0) mb[idx >> 6] = b;
}

// ---- Flash attention: LDS double-buffered via global_load_lds ------------
// Per kc-chunk (32 kpos): K-tile 4KB (32r x 128B swz) + VT-tile 4KB (64r x 64B swz)
// 2-phase: STAGE(next) || ds_read+compute(cur); __syncthreads drains vmcnt.
__global__ __launch_bounds__(256, 4) void attn_kernel(
    const unsigned short* __restrict__ Kb, const unsigned short* __restrict__ Qb,
    const unsigned short* __restrict__ VT, const uint32_t* __restrict__ maskw,
    unsigned short* __restrict__ Op) {
  __shared__ unsigned short lds[2][4096];   // [buf][K:0..2047 | VT:2048..4095]

  int bid = blockIdx.x;
  bid = (bid & 7) * 128 + (bid >> 3);  // XCD swizzle: 128-block chunks per XCD
  int qt = bid & 31;
  int h  = (bid >> 5) & 15;
  int n  = bid >> 9;
  int wave = threadIdx.x >> 6;
  int lane = threadIdx.x & 63;
  int g  = lane >> 4;              // lane group 0..3
  int qi = lane & 15;
  int qrow = qt * 64 + wave * 16 + qi;

  const unsigned short* qptr = Qb + (((size_t)n * NHEADS + h) * LSEQ + qrow) * HDIM;
  bf16x8 bq0 = *reinterpret_cast<const bf16x8*>(qptr + g * 8);        // d 0..31
  bf16x8 bq1 = *reinterpret_cast<const bf16x8*>(qptr + 32 + g * 8);   // d 32..63

  const unsigned short* khead  = Kb + (((size_t)n * NHEADS + h) * LSEQ) * HDIM;
  const unsigned short* vthead = VT + ((size_t)(n * NHEADS + h) * 64) * (HDIM * 32);
  const uint32_t* mrow = maskw + ((size_t)n * LSEQ + qrow) * 64;

  int toff = (int)threadIdx.x * 8;   // shorts: thread t stages bytes [16t,16t+16)

  // Loop-invariant LDS fragment offsets (shorts), swizzled
  int xk = qi & 7;
  int kA = qi * 64 + ((g ^ xk) << 3);
  int kB = qi * 64 + (((4 + g) ^ xk) << 3);
  int kC = kA + 1024;
  int kD = kB + 1024;
  int xv = (qi >> 1) & 3;
  int vA = qi * 32 + ((g ^ xv) << 3) + 2048;
  int vB = vA + 512;
  int vC = vA + 1024;
  int vD = vA + 1536;

  f32x4 z = {0.f, 0.f, 0.f, 0.f};
  f32x4 acc0 = z, acc1 = z, acc2 = z, acc3 = z;
  float ssum = 0.f;
  const float c  = 1.44269504088896f / 32.0f;
  const float mc = 96.0f * c;

#define STAGE(KC, BUF) do {                                                    \
    const unsigned short* kg_ = khead  + (size_t)(KC) * 2048 + toff;           \
    const unsigned short* vg_ = vthead + (size_t)(KC) * 2048 + toff;           \
    __builtin_amdgcn_global_load_lds(                                          \
        (const __attribute__((address_space(1))) uint32_t*)kg_,                \
        (__attribute__((address_space(3))) uint32_t*)&lds[BUF][wave * 512],    \
        16, 0, 0);                                                             \
    __builtin_amdgcn_global_load_lds(                                          \
        (const __attribute__((address_space(1))) uint32_t*)vg_,                \
        (__attribute__((address_space(3))) uint32_t*)&lds[BUF][2048 + wave * 512], \
        16, 0, 0);                                                             \
  } while (0)

#define COMPUTE(BUF, MW) do {                                                  \
    const unsigned short* lb_ = &lds[BUF][0];                                  \
    bf16x8 K0 = *(const bf16x8*)(lb_ + kA);                                    \
    bf16x8 K1 = *(const bf16x8*)(lb_ + kB);                                    \
    bf16x8 K2 = *(const bf16x8*)(lb_ + kC);                                    \
    bf16x8 K3 = *(const bf16x8*)(lb_ + kD);                                    \
    f32x4 e0 = z, e1 = z;                                                      \
    e0 = mfma16(K0, bq0, e0); e0 = mfma16(K1, bq1, e0);                        \
    e1 = mfma16(K2, bq0, e1); e1 = mfma16(K3, bq1, e1);                        \
    uint32_t m0_ = (MW) >> (4 * g);                                            \
    uint32_t m1_ = (MW) >> (16 + 4 * g);                                       \
    float p0 = (m0_ & 1u) ? __builtin_amdgcn_exp2f(e0[0] * c - mc) : 0.f;      \
    float p1 = (m0_ & 2u) ? __builtin_amdgcn_exp2f(e0[1] * c - mc) : 0.f;      \
    float p2 = (m0_ & 4u) ? __builtin_amdgcn_exp2f(e0[2] * c - mc) : 0.f;      \
    float p3 = (m0_ & 8u) ? __builtin_amdgcn_exp2f(e0[3] * c - mc) : 0.f;      \
    float p4 = (m1_ & 1u) ? __builtin_amdgcn_exp2f(e1[0] * c - mc) : 0.f;      \
    float p5 = (m1_ & 2u) ? __builtin_amdgcn_exp2f(e1[1] * c - mc) : 0.f;      \
    float p6 = (m1_ & 4u) ? __builtin_amdgcn_exp2f(e1[2] * c - mc) : 0.f;      \
    float p7 = (m1_ & 8u) ? __builtin_amdgcn_exp2f(e1[3] * c - mc) : 0.f;      \
    ssum += ((p0 + p1) + (p2 + p3)) + ((p4 + p5) + (p6 + p7));                 \
    uint32_t pk00, pk01, pk10, pk11;                                           \
    asm("v_cvt_pk_bf16_f32 %0, %1, %2" : "=v"(pk00) : "v"(p0), "v"(p1));       \
    asm("v_cvt_pk_bf16_f32 %0, %1, %2" : "=v"(pk01) : "v"(p2), "v"(p3));       \
    asm("v_cvt_pk_bf16_f32 %0, %1, %2" : "=v"(pk10) : "v"(p4), "v"(p5));       \
    asm("v_cvt_pk_bf16_f32 %0, %1, %2" : "=v"(pk11) : "v"(p6), "v"(p7));       \
    int srcA = ((g & 1) << 5) + qi;                                            \
    int srcB = srcA + 16;                                                      \
    uint32_t a0 = (uint32_t)__shfl((int)pk00, srcA, 64);                       \
    uint32_t a1 = (uint32_t)__shfl((int)pk01, srcA, 64);                       \
    uint32_t a2 = (uint32_t)__shfl((int)pk10, srcA, 64);                       \
    uint32_t a3 = (uint32_t)__shfl((int)pk11, srcA, 64);                       \
    uint32_t b0 = (uint32_t)__shfl((int)pk00, srcB, 64);                       \
    uint32_t b1 = (uint32_t)__shfl((int)pk01, srcB, 64);                       \
    uint32_t b2 = (uint32_t)__shfl((int)pk10, srcB, 64);                       \
    uint32_t b3 = (uint32_t)__shfl((int)pk11, srcB, 64);                       \
    bool th = g >= 2;                                                          \
    union { uint32_t u[4]; bf16x8 v; } pf;                                     \
    pf.u[0] = th ? a2 : a0;                                                    \
    pf.u[1] = th ? a3 : a1;                                                    \
    pf.u[2] = th ? b2 : b0;                                                    \
    pf.u[3] = th ? b3 : b1;                                                    \
    bf16x8 V0 = *(const bf16x8*)(lb_ + vA);                                    \
    bf16x8 V1 = *(const bf16x8*)(lb_ + vB);                                    \
    bf16x8 V2 = *(const bf16x8*)(lb_ + vC);                                    \
    bf16x8 V3 = *(const bf16x8*)(lb_ + vD);                                    \
    acc0 = mfma16(V0, pf.v, acc0);                                             \
    acc1 = mfma16(V1, pf.v, acc1);                                             \
    acc2 = mfma16(V2, pf.v, acc2);                                             \
    acc3 = mfma16(V3, pf.v, acc3);                                             \
  } while (0)

  uint32_t mw0 = mrow[0], mw1, mw2;
  STAGE(0, 0);
  __syncthreads();

  for (int kc = 0; kc < 64; kc += 2) {
    // phase A: stage kc+1 -> buf1, compute kc from buf0
    STAGE((kc + 1) & 63, 1);
    mw1 = mrow[(kc + 1) & 63];
    COMPUTE(0, mw0);
    __syncthreads();
    // phase B: stage kc+2 -> buf0, compute kc+1 from buf1
    STAGE((kc + 2) & 63, 0);
    mw2 = mrow[(kc + 2) & 63];
    COMPUTE(1, mw1);
    __syncthreads();
    mw0 = mw2;
  }
#undef STAGE
#undef COMPUTE

  ssum += __shfl_xor(ssum, 16, 64);
  ssum += __shfl_xor(ssum, 32, 64);
  float inv = 1.0f / ssum;

  // acc holds out^T[d][q]: lane q = qi, d = dsub*16 + 4g + r
  size_t ob = ((size_t)n * LSEQ + qrow) * EMB + h * HDIM;
  ushort4v s0, s1, s2, s3;
#pragma unroll
  for (int r = 0; r < 4; ++r) {
    s0[r] = f2bf(acc0[r] * inv);
    s1[r] = f2bf(acc1[r] * inv);
    s2[r] = f2bf(acc2[r] * inv);
    s3[r] = f2bf(acc3[r] * inv);
  }
  *reinterpret_cast<ushort4v*>(Op + ob + 0  + 4 * g) = s0;
  *reinterpret_cast<ushort4v*>(Op + ob + 16 + 4 * g) = s1;
  *reinterpret_cast<ushort4v*>(Op + ob + 32 + 4 * g) = s2;
  *reinterpret_cast<ushort4v*>(Op + ob + 48 + 4 * g) = s3;
}

// ---- Projection: out[m][j] = sum_k Op[m][k] * Wo[j][k] + bo[j] (fp32 out)
__global__ __launch_bounds__(256) void proj_kernel(
    const unsigned short* __restrict__ A, const unsigned short* __restrict__ B,
    const float* __restrict__ bo, float* __restrict__ out) {
  int bid = blockIdx.x;
  int mb = bid & 63;
  int nb = bid >> 6;
  int wave = threadIdx.x >> 6;
  int lane = threadIdx.x & 63;
  int g = lane >> 4, qi = lane & 15;
  const unsigned short* ap  = A + (size_t)(mb * 64 + wave * 16 + qi) * EMB;
  const unsigned short* bp  = B + (size_t)(nb * 64 + qi) * EMB;
  f32x4 z = {0.f, 0.f, 0.f, 0.f};
  f32x4 acc0 = z, acc1 = z, acc2 = z, acc3 = z;
  for (int kt = 0; kt < 32; ++kt) {
    bf16x8 a  = *(const bf16x8*)(ap + kt * 32 + g * 8);
    bf16x8 b0 = *(const bf16x8*)(bp + kt * 32 + g * 8);
    bf16x8 b1 = *(const bf16x8*)(bp + 16 * EMB + kt * 32 + g * 8);
    bf16x8 b2 = *(const bf16x8*)(bp + 32 * EMB + kt * 32 + g * 8);
    bf16x8 b3 = *(const bf16x8*)(bp + 48 * EMB + kt * 32 + g * 8);
    acc0 = mfma16(a, b0, acc0);
    acc1 = mfma16(a, b1, acc1);
    acc2 = mfma16(a, b2, acc2);
    acc3 = mfma16(a, b3, acc3);
  }
  int mrow = mb * 64 + wave * 16 + 4 * g;
#pragma unroll
  for (int r = 0; r < 4; ++r) {
    int row = mrow + r;
    int c0 = nb * 64 + qi;
    out[(size_t)row * EMB + c0]      = acc0[r] + bo[c0];
    out[(size_t)row * EMB + c0 + 16] = acc1[r] + bo[c0 + 16];
    out[(size_t)row * EMB + c0 + 32] = acc2[r] + bo[c0 + 32];
    out[(size_t)row * EMB + c0 + 48] = acc3[r] + bo[c0 + 48];
  }
}

extern "C" void kernel_launch(void* const* d_in, const int* in_sizes, int n_in,
                              void* d_out, int out_size, void* d_ws, size_t ws_size,
                              hipStream_t stream) {
  const float* Vf   = (const float*)d_in[0];
  const float* Kf   = (const float*)d_in[1];
  const float* Qf   = (const float*)d_in[2];
  const int*   Mask = (const int*)d_in[3];
  const float* Wo   = (const float*)d_in[4];
  const float* Bo   = (const float*)d_in[5];
  float* out = (float*)d_out;

  char* ws = (char*)d_ws;
  // ws layout (bytes): Qb 8MB | Kb 8MB | VT 8MB | Wob 2MB | Opb 8MB | Mb 1MB
  unsigned short* Qb  = (unsigned short*)(ws);
  unsigned short* Kb  = (unsigned short*)(ws + (size_t)8  * 1024 * 1024);
  unsigned short* VTb = (unsigned short*)(ws + (size_t)16 * 1024 * 1024);
  unsigned short* Wob = (unsigned short*)(ws + (size_t)24 * 1024 * 1024);
  unsigned short* Opb = (unsigned short*)(ws + (size_t)26 * 1024 * 1024);
  unsigned long long* Mb = (unsigned long long*)(ws + (size_t)34 * 1024 * 1024);

  convert_qk_kernel<<<8192, 256, 0, stream>>>(Qf, Kf, Qb, Kb);
  convert_vt_kernel<<<2048, 256, 0, stream>>>(Vf, VTb);
  convert_wo_kernel<<<1024, 256, 0, stream>>>(Wo, Wob);
  mask_bits_kernel<<<32768, 256, 0, stream>>>(Mask, Mb);
  attn_kernel<<<1024, 256, 0, stream>>>(Kb, Qb, VTb, (const uint32_t*)Mb, Opb);
  proj_kernel<<<1024, 256, 0, stream>>>(Opb, Wob, Bo, out);
}

// Round 4
// 96.248 us; speedup vs baseline: 3.3431x; 1.8060x over previous
//
#include <hip/hip_runtime.h>
#include <hip/hip_bf16.h>
#include <stdint.h>

#define LSEQ 2048
#define NBATCH 2
#define NHEADS 16
#define HDIM 64
#define EMB 1024

typedef __bf16 bf16x8 __attribute__((ext_vector_type(8)));
typedef float f32x4 __attribute__((ext_vector_type(4)));
typedef unsigned short ushort4v __attribute__((ext_vector_type(4)));
typedef unsigned short ushort8v __attribute__((ext_vector_type(8)));

static __device__ __forceinline__ unsigned short f2bf(float f) {
  union { float f; uint32_t u; } v; v.f = f;
  uint32_t u = v.u;
  u += 0x7fffu + ((u >> 16) & 1u);   // RNE
  return (unsigned short)(u >> 16);
}

static __device__ __forceinline__ f32x4 mfma16(bf16x8 a, bf16x8 b, f32x4 c) {
  return __builtin_amdgcn_mfma_f32_16x16x32_bf16(a, b, c, 0, 0, 0);
}

// ---- prep: Q,K convert (K row-swizzled), Wo convert, mask->bytes ---------
// blocks [0,8192): QK.  [8192,9216): Wo.  [9216,13312): mask bytes.
__global__ __launch_bounds__(256) void prep_kernel(
    const float* __restrict__ q, const float* __restrict__ k,
    const float* __restrict__ w, const int* __restrict__ mask,
    unsigned short* __restrict__ qb, unsigned short* __restrict__ kb,
    unsigned short* __restrict__ wb, unsigned char* __restrict__ mb8) {
  int b = blockIdx.x;
  if (b < 8192) {
    int idx = b * 256 + threadIdx.x;          // 2 * 2^20 float4 granules
    const float* src; unsigned short* dst; int t; int swz;
    if (idx < (1 << 20)) { src = q; dst = qb; t = idx; swz = 0; }
    else                 { src = k; dst = kb; t = idx - (1 << 20); swz = 1; }
    int e = t << 2;
    int d = e & 63;
    int h = (e >> 6) & 15;
    int l = (e >> 10) & (LSEQ - 1);
    int n = e >> 21;
    float4 v = reinterpret_cast<const float4*>(src)[t];
    ushort4v o;
    o.x = f2bf(v.x); o.y = f2bf(v.y); o.z = f2bf(v.z); o.w = f2bf(v.w);
    int dd = d;
    if (swz) dd = ((((d >> 3) ^ (l & 7)) << 3) | (d & 7));
    size_t oi = (((size_t)n * NHEADS + h) * LSEQ + l) * HDIM + dd;
    *reinterpret_cast<ushort4v*>(dst + oi) = o;
  } else if (b < 9216) {
    int t = (b - 8192) * 256 + threadIdx.x;   // 2^18 float4 granules
    float4 v = reinterpret_cast<const float4*>(w)[t];
    ushort4v o;
    o.x = f2bf(v.x); o.y = f2bf(v.y); o.z = f2bf(v.z); o.w = f2bf(v.w);
    reinterpret_cast<ushort4v*>(wb)[t] = o;
  } else {
    int idx = (b - 9216) * 256 + threadIdx.x; // 1M threads, 8 ints each
    const int* mp = mask + (size_t)idx * 8;
    int4 m0 = *reinterpret_cast<const int4*>(mp);
    int4 m1 = *reinterpret_cast<const int4*>(mp + 4);
    unsigned int bb = (m0.x ? 1u : 0u) | (m0.y ? 2u : 0u) | (m0.z ? 4u : 0u) |
                      (m0.w ? 8u : 0u) | (m1.x ? 16u : 0u) | (m1.y ? 32u : 0u) |
                      (m1.z ? 64u : 0u) | (m1.w ? 128u : 0u);
    mb8[idx] = (unsigned char)bb;
  }
}

// ---- V: f32 [n][l][h*64+d] -> bf16 VT chunks [n][h][kc][d][slot32] -------
// slot s: g=s>>3, j=s&7: kp(s) = (j<4) ? 4g+j : 16+4g+(j-4)   (PV B-frag order)
// 16B-granule bank swizzle: c' = c ^ ((d>>1)&3)
__global__ __launch_bounds__(256) void convert_vt_kernel(
    const float* __restrict__ v, unsigned short* __restrict__ vt) {
  int bid = blockIdx.x;            // n*16*64 + h*64 + kc
  int kc = bid & 63;
  int h  = (bid >> 6) & 15;
  int n  = bid >> 10;
  int t  = threadIdx.x;
  int d    = t & 63;               // consecutive lanes -> consecutive d: coalesced
  int sgrp = t >> 6;               // slot group: slots 8*sgrp..8*sgrp+7
  const float* src = v + (size_t)n * LSEQ * EMB + h * HDIM + d;
  ushort8v o;
#pragma unroll
  for (int j = 0; j < 8; ++j) {
    int kp = (j < 4) ? (4 * sgrp + j) : (16 + 4 * sgrp + (j - 4));
    float f = src[(size_t)(kc * 32 + kp) * EMB];
    o[j] = f2bf(f);
  }
  int cs = sgrp ^ ((d >> 1) & 3);
  size_t base = (((size_t)(n * NHEADS + h) * 64 + kc) * HDIM + d) * 32 + (cs << 3);
  *reinterpret_cast<ushort8v*>(vt + base) = o;
}

// ---- Flash attention: LDS dbuf via global_load_lds, KVBLK=64, no shuffles -
__global__ __launch_bounds__(256, 4) void attn_kernel(
    const unsigned short* __restrict__ Kb, const unsigned short* __restrict__ Qb,
    const unsigned short* __restrict__ VT, const uint32_t* __restrict__ maskw,
    unsigned short* __restrict__ Op) {
  __shared__ unsigned short lds[2][8192];  // [buf][K0|K1|V0|V1], 2048 shorts each

  int bid = blockIdx.x;
  bid = (bid & 7) * 128 + (bid >> 3);  // XCD swizzle
  int qt = bid & 31;
  int h  = (bid >> 5) & 15;
  int n  = bid >> 9;
  int tid  = threadIdx.x;
  int wave = tid >> 6;
  int lane = tid & 63;
  int g  = lane >> 4;
  int qi = lane & 15;
  int qrow = qt * 64 + wave * 16 + qi;

  const unsigned short* qptr = Qb + (((size_t)n * NHEADS + h) * LSEQ + qrow) * HDIM;
  bf16x8 bq0 = *reinterpret_cast<const bf16x8*>(qptr + g * 8);        // d 0..31
  bf16x8 bq1 = *reinterpret_cast<const bf16x8*>(qptr + 32 + g * 8);   // d 32..63

  const unsigned short* khead  = Kb + (((size_t)n * NHEADS + h) * LSEQ) * HDIM;
  const unsigned short* vthead = VT + ((size_t)(n * NHEADS + h) * 64) * (HDIM * 32);
  const uint32_t* mrow = maskw + ((size_t)n * LSEQ + qrow) * 64;

  // Loop-invariant LDS fragment offsets (shorts), swizzled
  int xk = qi & 7;
  int kA = qi * 64 + ((g ^ xk) << 3);
  int kB = qi * 64 + (((4 + g) ^ xk) << 3);
  int kC = kA + 1024;
  int kD = kB + 1024;
  int xv = (qi >> 1) & 3;
  int vA = qi * 32 + ((g ^ xv) << 3);
  int vB = vA + 512;
  int vC = vA + 1024;
  int vD = vA + 1536;

  f32x4 z = {0.f, 0.f, 0.f, 0.f};
  f32x4 acc0 = z, acc1 = z, acc2 = z, acc3 = z;
  float ssum = 0.f;
  const float c  = 1.44269504088896f / 32.0f;
  const float mc = 96.0f * 1.44269504088896f / 32.0f;

#define STAGE(T, BUF) do {                                                     \
    const unsigned short* kg_ = khead  + (size_t)(T) * 4096 + tid * 8;         \
    const unsigned short* vg_ = vthead + (size_t)(T) * 4096 + tid * 8;         \
    __builtin_amdgcn_global_load_lds(                                          \
        (const __attribute__((address_space(1))) uint32_t*)kg_,                \
        (__attribute__((address_space(3))) uint32_t*)&lds[BUF][wave * 512],    \
        16, 0, 0);                                                             \
    __builtin_amdgcn_global_load_lds(                                          \
        (const __attribute__((address_space(1))) uint32_t*)(kg_ + 2048),       \
        (__attribute__((address_space(3))) uint32_t*)&lds[BUF][2048 + wave * 512], \
        16, 0, 0);                                                             \
    __builtin_amdgcn_global_load_lds(                                          \
        (const __attribute__((address_space(1))) uint32_t*)vg_,                \
        (__attribute__((address_space(3))) uint32_t*)&lds[BUF][4096 + wave * 512], \
        16, 0, 0);                                                             \
    __builtin_amdgcn_global_load_lds(                                          \
        (const __attribute__((address_space(1))) uint32_t*)(vg_ + 2048),       \
        (__attribute__((address_space(3))) uint32_t*)&lds[BUF][6144 + wave * 512], \
        16, 0, 0);                                                             \
  } while (0)

#define COMPUTE(BUF, CH, MW) do {                                              \
    const unsigned short* lk_ = &lds[BUF][(CH) * 2048];                        \
    const unsigned short* lv_ = &lds[BUF][4096 + (CH) * 2048];                 \
    bf16x8 K0 = *(const bf16x8*)(lk_ + kA);                                    \
    bf16x8 K1 = *(const bf16x8*)(lk_ + kB);                                    \
    bf16x8 K2 = *(const bf16x8*)(lk_ + kC);                                    \
    bf16x8 K3 = *(const bf16x8*)(lk_ + kD);                                    \
    f32x4 e0 = z, e1 = z;                                                      \
    e0 = mfma16(K0, bq0, e0); e0 = mfma16(K1, bq1, e0);                        \
    e1 = mfma16(K2, bq0, e1); e1 = mfma16(K3, bq1, e1);                        \
    uint32_t m0_ = (MW) >> (4 * g);                                            \
    uint32_t m1_ = (MW) >> (16 + 4 * g);                                       \
    float p0 = (m0_ & 1u) ? __builtin_amdgcn_exp2f(__builtin_fmaf(e0[0], c, -mc)) : 0.f; \
    float p1 = (m0_ & 2u) ? __builtin_amdgcn_exp2f(__builtin_fmaf(e0[1], c, -mc)) : 0.f; \
    float p2 = (m0_ & 4u) ? __builtin_amdgcn_exp2f(__builtin_fmaf(e0[2], c, -mc)) : 0.f; \
    float p3 = (m0_ & 8u) ? __builtin_amdgcn_exp2f(__builtin_fmaf(e0[3], c, -mc)) : 0.f; \
    float p4 = (m1_ & 1u) ? __builtin_amdgcn_exp2f(__builtin_fmaf(e1[0], c, -mc)) : 0.f; \
    float p5 = (m1_ & 2u) ? __builtin_amdgcn_exp2f(__builtin_fmaf(e1[1], c, -mc)) : 0.f; \
    float p6 = (m1_ & 4u) ? __builtin_amdgcn_exp2f(__builtin_fmaf(e1[2], c, -mc)) : 0.f; \
    float p7 = (m1_ & 8u) ? __builtin_amdgcn_exp2f(__builtin_fmaf(e1[3], c, -mc)) : 0.f; \
    ssum += ((p0 + p1) + (p2 + p3)) + ((p4 + p5) + (p6 + p7));                 \
    union { uint32_t u[4]; bf16x8 v; } pf;                                     \
    asm("v_cvt_pk_bf16_f32 %0, %1, %2" : "=v"(pf.u[0]) : "v"(p0), "v"(p1));    \
    asm("v_cvt_pk_bf16_f32 %0, %1, %2" : "=v"(pf.u[1]) : "v"(p2), "v"(p3));    \
    asm("v_cvt_pk_bf16_f32 %0, %1, %2" : "=v"(pf.u[2]) : "v"(p4), "v"(p5));    \
    asm("v_cvt_pk_bf16_f32 %0, %1, %2" : "=v"(pf.u[3]) : "v"(p6), "v"(p7));    \
    bf16x8 V0 = *(const bf16x8*)(lv_ + vA);                                    \
    bf16x8 V1 = *(const bf16x8*)(lv_ + vB);                                    \
    bf16x8 V2 = *(const bf16x8*)(lv_ + vC);                                    \
    bf16x8 V3 = *(const bf16x8*)(lv_ + vD);                                    \
    acc0 = mfma16(V0, pf.v, acc0);                                             \
    acc1 = mfma16(V1, pf.v, acc1);                                             \
    acc2 = mfma16(V2, pf.v, acc2);                                             \
    acc3 = mfma16(V3, pf.v, acc3);                                             \
  } while (0)

  uint64_t mp0 = *(const uint64_t*)(mrow);
  uint64_t mp1, mp2;
  STAGE(0, 0);
  __syncthreads();

  for (int t = 0; t < 32; t += 2) {
    int t1 = (t + 1) & 31;
    mp1 = *(const uint64_t*)(mrow + 2 * t1);
    STAGE(t1, 1);
    COMPUTE(0, 0, (uint32_t)mp0);
    COMPUTE(0, 1, (uint32_t)(mp0 >> 32));
    __syncthreads();
    int t2 = (t + 2) & 31;
    mp2 = *(const uint64_t*)(mrow + 2 * t2);
    STAGE(t2, 0);
    COMPUTE(1, 0, (uint32_t)mp1);
    COMPUTE(1, 1, (uint32_t)(mp1 >> 32));
    __syncthreads();
    mp0 = mp2;
  }
#undef STAGE
#undef COMPUTE

  ssum += __shfl_xor(ssum, 16, 64);
  ssum += __shfl_xor(ssum, 32, 64);
  float inv = 1.0f / ssum;

  size_t ob = ((size_t)n * LSEQ + qrow) * EMB + h * HDIM;
  ushort4v s0, s1, s2, s3;
#pragma unroll
  for (int r = 0; r < 4; ++r) {
    s0[r] = f2bf(acc0[r] * inv);
    s1[r] = f2bf(acc1[r] * inv);
    s2[r] = f2bf(acc2[r] * inv);
    s3[r] = f2bf(acc3[r] * inv);
  }
  *reinterpret_cast<ushort4v*>(Op + ob + 0  + 4 * g) = s0;
  *reinterpret_cast<ushort4v*>(Op + ob + 16 + 4 * g) = s1;
  *reinterpret_cast<ushort4v*>(Op + ob + 32 + 4 * g) = s2;
  *reinterpret_cast<ushort4v*>(Op + ob + 48 + 4 * g) = s3;
}

// ---- Projection: 128x64 block tile, LDS dbuf, out = A @ Wo^T + bo (fp32) --
__global__ __launch_bounds__(256, 2) void proj_kernel(
    const unsigned short* __restrict__ A, const unsigned short* __restrict__ B,
    const float* __restrict__ bo, float* __restrict__ out) {
  __shared__ unsigned short plds[2][6144];  // [buf][A: 0..4096 | B: 4096..6144]

  int bid = blockIdx.x;
  bid = (bid & 7) * 64 + (bid >> 3);  // XCD swizzle (512 blocks)
  int mb0 = (bid >> 4) * 128;
  int nb0 = (bid & 15) * 64;
  int tid  = threadIdx.x;
  int wave = tid >> 6;
  int lane = tid & 63;
  int g  = lane >> 4;
  int qi = lane & 15;
  int wm = wave >> 1, wn = wave & 1;

  // staging source (inverse-swizzled global read -> linear LDS dest)
  int srow = tid >> 2;
  int scol = (((tid & 3) ^ ((tid >> 3) & 3)) << 3);
  const unsigned short* aS0 = A + (size_t)(mb0 + srow) * EMB + scol;
  const unsigned short* aS1 = aS0 + (size_t)64 * EMB;
  const unsigned short* bS  = B + (size_t)(nb0 + srow) * EMB + scol;

  // swizzled ds_read offsets (shorts)
  int xa = (qi >> 1) & 3;
  int gof = ((g ^ xa) << 3);
  int aof0 = (wm * 64 + qi) * 32 + gof;
  int aof1 = aof0 + 16 * 32;
  int aof2 = aof0 + 32 * 32;
  int aof3 = aof0 + 48 * 32;
  int bof0 = (wn * 32 + qi) * 32 + gof;
  int bof1 = bof0 + 16 * 32;

  f32x4 z = {0.f, 0.f, 0.f, 0.f};
  f32x4 acc00 = z, acc01 = z, acc10 = z, acc11 = z;
  f32x4 acc20 = z, acc21 = z, acc30 = z, acc31 = z;

#define PSTAGE(KT, BUF) do {                                                   \
    __builtin_amdgcn_global_load_lds(                                          \
        (const __attribute__((address_space(1))) uint32_t*)(aS0 + (KT) * 32),  \
        (__attribute__((address_space(3))) uint32_t*)&plds[BUF][wave * 512],   \
        16, 0, 0);                                                             \
    __builtin_amdgcn_global_load_lds(                                          \
        (const __attribute__((address_space(1))) uint32_t*)(aS1 + (KT) * 32),  \
        (__attribute__((address_space(3))) uint32_t*)&plds[BUF][2048 + wave * 512], \
        16, 0, 0);                                                             \
    __builtin_amdgcn_global_load_lds(                                          \
        (const __attribute__((address_space(1))) uint32_t*)(bS + (KT) * 32),   \
        (__attribute__((address_space(3))) uint32_t*)&plds[BUF][4096 + wave * 512], \
        16, 0, 0);                                                             \
  } while (0)

#define PCOMPUTE(BUF) do {                                                     \
    const unsigned short* la_ = &plds[BUF][0];                                 \
    const unsigned short* lb_ = &plds[BUF][4096];                              \
    bf16x8 a0 = *(const bf16x8*)(la_ + aof0);                                  \
    bf16x8 a1 = *(const bf16x8*)(la_ + aof1);                                  \
    bf16x8 a2 = *(const bf16x8*)(la_ + aof2);                                  \
    bf16x8 a3 = *(const bf16x8*)(la_ + aof3);                                  \
    bf16x8 b0 = *(const bf16x8*)(lb_ + bof0);                                  \
    bf16x8 b1 = *(const bf16x8*)(lb_ + bof1);                                  \
    acc00 = mfma16(a0, b0, acc00); acc01 = mfma16(a0, b1, acc01);              \
    acc10 = mfma16(a1, b0, acc10); acc11 = mfma16(a1, b1, acc11);              \
    acc20 = mfma16(a2, b0, acc20); acc21 = mfma16(a2, b1, acc21);              \
    acc30 = mfma16(a3, b0, acc30); acc31 = mfma16(a3, b1, acc31);              \
  } while (0)

  PSTAGE(0, 0);
  __syncthreads();
  for (int kt = 0; kt < 32; kt += 2) {
    PSTAGE(kt + 1, 1);
    PCOMPUTE(0);
    __syncthreads();
    PSTAGE((kt + 2) & 31, 0);
    PCOMPUTE(1);
    __syncthreads();
  }
#undef PSTAGE
#undef PCOMPUTE

  int orow = mb0 + wm * 64 + 4 * g;
  int col0 = nb0 + wn * 32 + qi;
  float bia0 = bo[col0];
  float bia1 = bo[col0 + 16];
#define PSTORE(ACC0, ACC1, M) do {                                             \
    _Pragma("unroll")                                                          \
    for (int r = 0; r < 4; ++r) {                                              \
      size_t rw = (size_t)(orow + (M) * 16 + r) * EMB;                         \
      out[rw + col0]      = ACC0[r] + bia0;                                    \
      out[rw + col0 + 16] = ACC1[r] + bia1;                                    \
    }                                                                          \
  } while (0)
  PSTORE(acc00, acc01, 0);
  PSTORE(acc10, acc11, 1);
  PSTORE(acc20, acc21, 2);
  PSTORE(acc30, acc31, 3);
#undef PSTORE
}

extern "C" void kernel_launch(void* const* d_in, const int* in_sizes, int n_in,
                              void* d_out, int out_size, void* d_ws, size_t ws_size,
                              hipStream_t stream) {
  const float* Vf   = (const float*)d_in[0];
  const float* Kf   = (const float*)d_in[1];
  const float* Qf   = (const float*)d_in[2];
  const int*   Mask = (const int*)d_in[3];
  const float* Wo   = (const float*)d_in[4];
  const float* Bo   = (const float*)d_in[5];
  float* out = (float*)d_out;

  char* ws = (char*)d_ws;
  // ws layout (bytes): Qb 8MB | Kb 8MB | VT 8MB | Wob 2MB | Opb 8MB | Mb 1MB
  unsigned short* Qb  = (unsigned short*)(ws);
  unsigned short* Kb  = (unsigned short*)(ws + (size_t)8  * 1024 * 1024);
  unsigned short* VTb = (unsigned short*)(ws + (size_t)16 * 1024 * 1024);
  unsigned short* Wob = (unsigned short*)(ws + (size_t)24 * 1024 * 1024);
  unsigned short* Opb = (unsigned short*)(ws + (size_t)26 * 1024 * 1024);
  unsigned char*  Mb  = (unsigned char*)(ws + (size_t)34 * 1024 * 1024);

  prep_kernel<<<13312, 256, 0, stream>>>(Qf, Kf, Wo, Mask, Qb, Kb, Wob, Mb);
  convert_vt_kernel<<<2048, 256, 0, stream>>>(Vf, VTb);
  attn_kernel<<<1024, 256, 0, stream>>>(Kb, Qb, VTb, (const uint32_t*)Mb, Opb);
  proj_kernel<<<512, 256, 0, stream>>>(Opb, Wob, Bo, out);
}

// Round 5
// 90.593 us; speedup vs baseline: 3.5517x; 1.0624x over previous
//
#include <hip/hip_runtime.h>
#include <hip/hip_bf16.h>
#include <stdint.h>

#define LSEQ 2048
#define NBATCH 2
#define NHEADS 16
#define HDIM 64
#define EMB 1024

typedef __bf16 bf16x8 __attribute__((ext_vector_type(8)));
typedef float f32x4 __attribute__((ext_vector_type(4)));
typedef unsigned short ushort4v __attribute__((ext_vector_type(4)));
typedef unsigned short ushort8v __attribute__((ext_vector_type(8)));

// Q is prescaled by c = log2e/32 so QK^T MFMA yields log2-domain logits
// directly; the fixed-max bias 2^(-96c) cancels in acc/ssum (p <= ~4).
#define QSCALE (1.44269504088896f / 32.0f)

static __device__ __forceinline__ unsigned short f2bf(float f) {
  union { float f; uint32_t u; } v; v.f = f;
  uint32_t u = v.u;
  u += 0x7fffu + ((u >> 16) & 1u);   // RNE
  return (unsigned short)(u >> 16);
}

static __device__ __forceinline__ f32x4 mfma16(bf16x8 a, bf16x8 b, f32x4 c) {
  return __builtin_amdgcn_mfma_f32_16x16x32_bf16(a, b, c, 0, 0, 0);
}

// masked exp2: bit b of m selects exp2(e) or 0.0 (2 VALU: sbfe + and)
static __device__ __forceinline__ float mexp2(float e, uint32_t m, int b) {
  uint32_t keep = (uint32_t)__builtin_amdgcn_sbfe((int)m, b, 1);
  return __uint_as_float(__float_as_uint(__builtin_amdgcn_exp2f(e)) & keep);
}

// ---- prep: Q(scaled),K(swizzled) convert, Wo convert, mask->bytes, VT ----
// blocks [0,8192): QK. [8192,9216): Wo. [9216,13312): mask. [13312,15360): VT.
__global__ __launch_bounds__(256) void prep_kernel(
    const float* __restrict__ q, const float* __restrict__ k,
    const float* __restrict__ w, const int* __restrict__ mask,
    const float* __restrict__ v,
    unsigned short* __restrict__ qb, unsigned short* __restrict__ kb,
    unsigned short* __restrict__ wb, unsigned char* __restrict__ mb8,
    unsigned short* __restrict__ vt) {
  int b = blockIdx.x;
  if (b < 8192) {
    int idx = b * 256 + threadIdx.x;          // 2 * 2^20 float4 granules
    const float* src; unsigned short* dst; int t; int swz;
    if (idx < (1 << 20)) { src = q; dst = qb; t = idx; swz = 0; }
    else                 { src = k; dst = kb; t = idx - (1 << 20); swz = 1; }
    int e = t << 2;
    int d = e & 63;
    int h = (e >> 6) & 15;
    int l = (e >> 10) & (LSEQ - 1);
    int n = e >> 21;
    float4 vv = reinterpret_cast<const float4*>(src)[t];
    int dd = d;
    if (swz) dd = ((((d >> 3) ^ (l & 7)) << 3) | (d & 7));
    else { vv.x *= QSCALE; vv.y *= QSCALE; vv.z *= QSCALE; vv.w *= QSCALE; }
    ushort4v o;
    o.x = f2bf(vv.x); o.y = f2bf(vv.y); o.z = f2bf(vv.z); o.w = f2bf(vv.w);
    size_t oi = (((size_t)n * NHEADS + h) * LSEQ + l) * HDIM + dd;
    *reinterpret_cast<ushort4v*>(dst + oi) = o;
  } else if (b < 9216) {
    int t = (b - 8192) * 256 + threadIdx.x;   // 2^18 float4 granules
    float4 vv = reinterpret_cast<const float4*>(w)[t];
    ushort4v o;
    o.x = f2bf(vv.x); o.y = f2bf(vv.y); o.z = f2bf(vv.z); o.w = f2bf(vv.w);
    reinterpret_cast<ushort4v*>(wb)[t] = o;
  } else if (b < 13312) {
    int idx = (b - 9216) * 256 + threadIdx.x; // 1M threads, 8 ints each
    const int* mp = mask + (size_t)idx * 8;
    int4 m0 = *reinterpret_cast<const int4*>(mp);
    int4 m1 = *reinterpret_cast<const int4*>(mp + 4);
    unsigned int bb = (m0.x ? 1u : 0u) | (m0.y ? 2u : 0u) | (m0.z ? 4u : 0u) |
                      (m0.w ? 8u : 0u) | (m1.x ? 16u : 0u) | (m1.y ? 32u : 0u) |
                      (m1.z ? 64u : 0u) | (m1.w ? 128u : 0u);
    mb8[idx] = (unsigned char)bb;
  } else {
    // V -> VT chunks [n][h][kc][d][slot32]; slot order = PV B-frag order:
    // slot s (g=s>>3, j=s&7): kp = (j<4) ? 4g+j : 16+4g+(j-4)
    // 16B-granule bank swizzle: c' = c ^ ((d>>1)&3)
    int b2 = b - 13312;              // n*16*64 + h*64 + kc
    int kc = b2 & 63;
    int h  = (b2 >> 6) & 15;
    int n  = b2 >> 10;
    int t  = threadIdx.x;
    int d    = t & 63;
    int sgrp = t >> 6;
    const float* src = v + (size_t)n * LSEQ * EMB + h * HDIM + d;
    ushort8v o;
#pragma unroll
    for (int j = 0; j < 8; ++j) {
      int kp = (j < 4) ? (4 * sgrp + j) : (16 + 4 * sgrp + (j - 4));
      float f = src[(size_t)(kc * 32 + kp) * EMB];
      o[j] = f2bf(f);
    }
    int cs = sgrp ^ ((d >> 1) & 3);
    size_t base = (((size_t)(n * NHEADS + h) * 64 + kc) * HDIM + d) * 32 + (cs << 3);
    *reinterpret_cast<ushort8v*>(vt + base) = o;
  }
}

// ---- Flash attention: LDS dbuf via global_load_lds, KVBLK=64, no shuffles -
__global__ __launch_bounds__(256, 4) void attn_kernel(
    const unsigned short* __restrict__ Kb, const unsigned short* __restrict__ Qb,
    const unsigned short* __restrict__ VT, const uint32_t* __restrict__ maskw,
    unsigned short* __restrict__ Op) {
  __shared__ unsigned short lds[2][8192];  // [buf][K0|K1|V0|V1], 2048 shorts each

  int bid = blockIdx.x;
  bid = (bid & 7) * 128 + (bid >> 3);  // XCD swizzle
  int qt = bid & 31;
  int h  = (bid >> 5) & 15;
  int n  = bid >> 9;
  int tid  = threadIdx.x;
  int wave = tid >> 6;
  int lane = tid & 63;
  int g  = lane >> 4;
  int qi = lane & 15;
  int qrow = qt * 64 + wave * 16 + qi;

  const unsigned short* qptr = Qb + (((size_t)n * NHEADS + h) * LSEQ + qrow) * HDIM;
  bf16x8 bq0 = *reinterpret_cast<const bf16x8*>(qptr + g * 8);        // d 0..31
  bf16x8 bq1 = *reinterpret_cast<const bf16x8*>(qptr + 32 + g * 8);   // d 32..63

  const unsigned short* khead  = Kb + (((size_t)n * NHEADS + h) * LSEQ) * HDIM;
  const unsigned short* vthead = VT + ((size_t)(n * NHEADS + h) * 64) * (HDIM * 32);
  const uint32_t* mrow = maskw + ((size_t)n * LSEQ + qrow) * 64;

  // Loop-invariant LDS fragment offsets (shorts), swizzled
  int xk = qi & 7;
  int kA = qi * 64 + ((g ^ xk) << 3);
  int kB = qi * 64 + (((4 + g) ^ xk) << 3);
  int kC = kA + 1024;
  int kD = kB + 1024;
  int xv = (qi >> 1) & 3;
  int vA = qi * 32 + ((g ^ xv) << 3);
  int vB = vA + 512;
  int vC = vA + 1024;
  int vD = vA + 1536;

  f32x4 z = {0.f, 0.f, 0.f, 0.f};
  f32x4 acc0 = z, acc1 = z, acc2 = z, acc3 = z;
  float ssum = 0.f;

#define STAGE(T, BUF) do {                                                     \
    const unsigned short* kg_ = khead  + (size_t)(T) * 4096 + tid * 8;         \
    const unsigned short* vg_ = vthead + (size_t)(T) * 4096 + tid * 8;         \
    __builtin_amdgcn_global_load_lds(                                          \
        (const __attribute__((address_space(1))) uint32_t*)kg_,                \
        (__attribute__((address_space(3))) uint32_t*)&lds[BUF][wave * 512],    \
        16, 0, 0);                                                             \
    __builtin_amdgcn_global_load_lds(                                          \
        (const __attribute__((address_space(1))) uint32_t*)(kg_ + 2048),       \
        (__attribute__((address_space(3))) uint32_t*)&lds[BUF][2048 + wave * 512], \
        16, 0, 0);                                                             \
    __builtin_amdgcn_global_load_lds(                                          \
        (const __attribute__((address_space(1))) uint32_t*)vg_,                \
        (__attribute__((address_space(3))) uint32_t*)&lds[BUF][4096 + wave * 512], \
        16, 0, 0);                                                             \
    __builtin_amdgcn_global_load_lds(                                          \
        (const __attribute__((address_space(1))) uint32_t*)(vg_ + 2048),       \
        (__attribute__((address_space(3))) uint32_t*)&lds[BUF][6144 + wave * 512], \
        16, 0, 0);                                                             \
  } while (0)

#define COMPUTE(BUF, CH, MW) do {                                              \
    const unsigned short* lk_ = &lds[BUF][(CH) * 2048];                        \
    const unsigned short* lv_ = &lds[BUF][4096 + (CH) * 2048];                 \
    bf16x8 K0 = *(const bf16x8*)(lk_ + kA);                                    \
    bf16x8 K1 = *(const bf16x8*)(lk_ + kB);                                    \
    bf16x8 K2 = *(const bf16x8*)(lk_ + kC);                                    \
    bf16x8 K3 = *(const bf16x8*)(lk_ + kD);                                    \
    f32x4 e0 = z, e1 = z;                                                      \
    e0 = mfma16(K0, bq0, e0); e0 = mfma16(K1, bq1, e0);                        \
    e1 = mfma16(K2, bq0, e1); e1 = mfma16(K3, bq1, e1);                        \
    uint32_t m0_ = (MW) >> (4 * g);                                            \
    uint32_t m1_ = (MW) >> (16 + 4 * g);                                       \
    float p0 = mexp2(e0[0], m0_, 0);                                           \
    float p1 = mexp2(e0[1], m0_, 1);                                           \
    float p2 = mexp2(e0[2], m0_, 2);                                           \
    float p3 = mexp2(e0[3], m0_, 3);                                           \
    float p4 = mexp2(e1[0], m1_, 0);                                           \
    float p5 = mexp2(e1[1], m1_, 1);                                           \
    float p6 = mexp2(e1[2], m1_, 2);                                           \
    float p7 = mexp2(e1[3], m1_, 3);                                           \
    ssum += ((p0 + p1) + (p2 + p3)) + ((p4 + p5) + (p6 + p7));                 \
    union { uint32_t u[4]; bf16x8 v; } pf;                                     \
    asm("v_cvt_pk_bf16_f32 %0, %1, %2" : "=v"(pf.u[0]) : "v"(p0), "v"(p1));    \
    asm("v_cvt_pk_bf16_f32 %0, %1, %2" : "=v"(pf.u[1]) : "v"(p2), "v"(p3));    \
    asm("v_cvt_pk_bf16_f32 %0, %1, %2" : "=v"(pf.u[2]) : "v"(p4), "v"(p5));    \
    asm("v_cvt_pk_bf16_f32 %0, %1, %2" : "=v"(pf.u[3]) : "v"(p6), "v"(p7));    \
    bf16x8 V0 = *(const bf16x8*)(lv_ + vA);                                    \
    bf16x8 V1 = *(const bf16x8*)(lv_ + vB);                                    \
    bf16x8 V2 = *(const bf16x8*)(lv_ + vC);                                    \
    bf16x8 V3 = *(const bf16x8*)(lv_ + vD);                                    \
    acc0 = mfma16(V0, pf.v, acc0);                                             \
    acc1 = mfma16(V1, pf.v, acc1);                                             \
    acc2 = mfma16(V2, pf.v, acc2);                                             \
    acc3 = mfma16(V3, pf.v, acc3);                                             \
  } while (0)

  uint64_t mp0 = *(const uint64_t*)(mrow);
  uint64_t mp1, mp2;
  STAGE(0, 0);
  __syncthreads();

  for (int t = 0; t < 32; t += 2) {
    int t1 = (t + 1) & 31;
    mp1 = *(const uint64_t*)(mrow + 2 * t1);
    STAGE(t1, 1);
    COMPUTE(0, 0, (uint32_t)mp0);
    COMPUTE(0, 1, (uint32_t)(mp0 >> 32));
    __syncthreads();
    int t2 = (t + 2) & 31;
    mp2 = *(const uint64_t*)(mrow + 2 * t2);
    STAGE(t2, 0);
    COMPUTE(1, 0, (uint32_t)mp1);
    COMPUTE(1, 1, (uint32_t)(mp1 >> 32));
    __syncthreads();
    mp0 = mp2;
  }
#undef STAGE
#undef COMPUTE

  ssum += __shfl_xor(ssum, 16, 64);
  ssum += __shfl_xor(ssum, 32, 64);
  float inv = 1.0f / ssum;

  size_t ob = ((size_t)n * LSEQ + qrow) * EMB + h * HDIM;
  ushort4v s0, s1, s2, s3;
#pragma unroll
  for (int r = 0; r < 4; ++r) {
    s0[r] = f2bf(acc0[r] * inv);
    s1[r] = f2bf(acc1[r] * inv);
    s2[r] = f2bf(acc2[r] * inv);
    s3[r] = f2bf(acc3[r] * inv);
  }
  *reinterpret_cast<ushort4v*>(Op + ob + 0  + 4 * g) = s0;
  *reinterpret_cast<ushort4v*>(Op + ob + 16 + 4 * g) = s1;
  *reinterpret_cast<ushort4v*>(Op + ob + 32 + 4 * g) = s2;
  *reinterpret_cast<ushort4v*>(Op + ob + 48 + 4 * g) = s3;
}

// ---- Projection: 128x64 block tile, LDS dbuf, out = A @ Wo^T + bo (fp32) --
__global__ __launch_bounds__(256, 2) void proj_kernel(
    const unsigned short* __restrict__ A, const unsigned short* __restrict__ B,
    const float* __restrict__ bo, float* __restrict__ out) {
  __shared__ unsigned short plds[2][6144];  // [buf][A: 0..4096 | B: 4096..6144]

  int bid = blockIdx.x;
  bid = (bid & 7) * 64 + (bid >> 3);  // XCD swizzle (512 blocks)
  int mb0 = (bid >> 4) * 128;
  int nb0 = (bid & 15) * 64;
  int tid  = threadIdx.x;
  int wave = tid >> 6;
  int lane = tid & 63;
  int g  = lane >> 4;
  int qi = lane & 15;
  int wm = wave >> 1, wn = wave & 1;

  // staging source (inverse-swizzled global read -> linear LDS dest)
  int srow = tid >> 2;
  int scol = (((tid & 3) ^ ((tid >> 3) & 3)) << 3);
  const unsigned short* aS0 = A + (size_t)(mb0 + srow) * EMB + scol;
  const unsigned short* aS1 = aS0 + (size_t)64 * EMB;
  const unsigned short* bS  = B + (size_t)(nb0 + srow) * EMB + scol;

  // swizzled ds_read offsets (shorts)
  int xa = (qi >> 1) & 3;
  int gof = ((g ^ xa) << 3);
  int aof0 = (wm * 64 + qi) * 32 + gof;
  int aof1 = aof0 + 16 * 32;
  int aof2 = aof0 + 32 * 32;
  int aof3 = aof0 + 48 * 32;
  int bof0 = (wn * 32 + qi) * 32 + gof;
  int bof1 = bof0 + 16 * 32;

  f32x4 z = {0.f, 0.f, 0.f, 0.f};
  f32x4 acc00 = z, acc01 = z, acc10 = z, acc11 = z;
  f32x4 acc20 = z, acc21 = z, acc30 = z, acc31 = z;

#define PSTAGE(KT, BUF) do {                                                   \
    __builtin_amdgcn_global_load_lds(                                          \
        (const __attribute__((address_space(1))) uint32_t*)(aS0 + (KT) * 32),  \
        (__attribute__((address_space(3))) uint32_t*)&plds[BUF][wave * 512],   \
        16, 0, 0);                                                             \
    __builtin_amdgcn_global_load_lds(                                          \
        (const __attribute__((address_space(1))) uint32_t*)(aS1 + (KT) * 32),  \
        (__attribute__((address_space(3))) uint32_t*)&plds[BUF][2048 + wave * 512], \
        16, 0, 0);                                                             \
    __builtin_amdgcn_global_load_lds(                                          \
        (const __attribute__((address_space(1))) uint32_t*)(bS + (KT) * 32),   \
        (__attribute__((address_space(3))) uint32_t*)&plds[BUF][4096 + wave * 512], \
        16, 0, 0);                                                             \
  } while (0)

#define PCOMPUTE(BUF) do {                                                     \
    const unsigned short* la_ = &plds[BUF][0];                                 \
    const unsigned short* lb_ = &plds[BUF][4096];                              \
    bf16x8 a0 = *(const bf16x8*)(la_ + aof0);                                  \
    bf16x8 a1 = *(const bf16x8*)(la_ + aof1);                                  \
    bf16x8 a2 = *(const bf16x8*)(la_ + aof2);                                  \
    bf16x8 a3 = *(const bf16x8*)(la_ + aof3);                                  \
    bf16x8 b0 = *(const bf16x8*)(lb_ + bof0);                                  \
    bf16x8 b1 = *(const bf16x8*)(lb_ + bof1);                                  \
    acc00 = mfma16(a0, b0, acc00); acc01 = mfma16(a0, b1, acc01);              \
    acc10 = mfma16(a1, b0, acc10); acc11 = mfma16(a1, b1, acc11);              \
    acc20 = mfma16(a2, b0, acc20); acc21 = mfma16(a2, b1, acc21);              \
    acc30 = mfma16(a3, b0, acc30); acc31 = mfma16(a3, b1, acc31);              \
  } while (0)

  PSTAGE(0, 0);
  __syncthreads();
  for (int kt = 0; kt < 32; kt += 2) {
    PSTAGE(kt + 1, 1);
    PCOMPUTE(0);
    __syncthreads();
    PSTAGE((kt + 2) & 31, 0);
    PCOMPUTE(1);
    __syncthreads();
  }
#undef PSTAGE
#undef PCOMPUTE

  int orow = mb0 + wm * 64 + 4 * g;
  int col0 = nb0 + wn * 32 + qi;
  float bia0 = bo[col0];
  float bia1 = bo[col0 + 16];
#define PSTORE(ACC0, ACC1, M) do {                                             \
    _Pragma("unroll")                                                          \
    for (int r = 0; r < 4; ++r) {                                              \
      size_t rw = (size_t)(orow + (M) * 16 + r) * EMB;                         \
      out[rw + col0]      = ACC0[r] + bia0;                                    \
      out[rw + col0 + 16] = ACC1[r] + bia1;                                    \
    }                                                                          \
  } while (0)
  PSTORE(acc00, acc01, 0);
  PSTORE(acc10, acc11, 1);
  PSTORE(acc20, acc21, 2);
  PSTORE(acc30, acc31, 3);
#undef PSTORE
}

extern "C" void kernel_launch(void* const* d_in, const int* in_sizes, int n_in,
                              void* d_out, int out_size, void* d_ws, size_t ws_size,
                              hipStream_t stream) {
  const float* Vf   = (const float*)d_in[0];
  const float* Kf   = (const float*)d_in[1];
  const float* Qf   = (const float*)d_in[2];
  const int*   Mask = (const int*)d_in[3];
  const float* Wo   = (const float*)d_in[4];
  const float* Bo   = (const float*)d_in[5];
  float* out = (float*)d_out;

  char* ws = (char*)d_ws;
  // ws layout (bytes): Qb 8MB | Kb 8MB | VT 8MB | Wob 2MB | Opb 8MB | Mb 1MB
  unsigned short* Qb  = (unsigned short*)(ws);
  unsigned short* Kb  = (unsigned short*)(ws + (size_t)8  * 1024 * 1024);
  unsigned short* VTb = (unsigned short*)(ws + (size_t)16 * 1024 * 1024);
  unsigned short* Wob = (unsigned short*)(ws + (size_t)24 * 1024 * 1024);
  unsigned short* Opb = (unsigned short*)(ws + (size_t)26 * 1024 * 1024);
  unsigned char*  Mb  = (unsigned char*)(ws + (size_t)34 * 1024 * 1024);

  prep_kernel<<<15360, 256, 0, stream>>>(Qf, Kf, Wo, Mask, Vf, Qb, Kb, Wob, Mb, VTb);
  attn_kernel<<<1024, 256, 0, stream>>>(Kb, Qb, VTb, (const uint32_t*)Mb, Opb);
  proj_kernel<<<512, 256, 0, stream>>>(Opb, Wob, Bo, out);
}

// Round 7
// 89.480 us; speedup vs baseline: 3.5959x; 1.0124x over previous
//
#include <hip/hip_runtime.h>
#include <hip/hip_bf16.h>
#include <stdint.h>

#define LSEQ 2048
#define NBATCH 2
#define NHEADS 16
#define HDIM 64
#define EMB 1024

typedef __bf16 bf16x8 __attribute__((ext_vector_type(8)));
typedef float f32x4 __attribute__((ext_vector_type(4)));
typedef unsigned short ushort4v __attribute__((ext_vector_type(4)));
typedef unsigned short ushort8v __attribute__((ext_vector_type(8)));

// Q is prescaled by c = log2e/32 so QK^T MFMA yields log2-domain logits
// directly; the fixed-max bias 2^(-96c) cancels in acc/ssum (p <= ~4).
#define QSCALE (1.44269504088896f / 32.0f)

static __device__ __forceinline__ unsigned short f2bf(float f) {
  union { float f; uint32_t u; } v; v.f = f;
  uint32_t u = v.u;
  u += 0x7fffu + ((u >> 16) & 1u);   // RNE
  return (unsigned short)(u >> 16);
}

static __device__ __forceinline__ f32x4 mfma16(bf16x8 a, bf16x8 b, f32x4 c) {
  return __builtin_amdgcn_mfma_f32_16x16x32_bf16(a, b, c, 0, 0, 0);
}

// masked exp2: bit b of m selects exp2(e) or 0.0 (2 VALU: sbfe + and)
static __device__ __forceinline__ float mexp2(float e, uint32_t m, int b) {
  uint32_t keep = (uint32_t)__builtin_amdgcn_sbfe((int)m, b, 1);
  return __uint_as_float(__float_as_uint(__builtin_amdgcn_exp2f(e)) & keep);
}

// ---- prep: Q(scaled),K(swizzled) convert, Wo convert, mask->bytes, VT ----
// blocks [0,8192): QK. [8192,9216): Wo. [9216,13312): mask. [13312,15360): VT.
__global__ __launch_bounds__(256) void prep_kernel(
    const float* __restrict__ q, const float* __restrict__ k,
    const float* __restrict__ w, const int* __restrict__ mask,
    const float* __restrict__ v,
    unsigned short* __restrict__ qb, unsigned short* __restrict__ kb,
    unsigned short* __restrict__ wb, unsigned char* __restrict__ mb8,
    unsigned short* __restrict__ vt) {
  int b = blockIdx.x;
  if (b < 8192) {
    int idx = b * 256 + threadIdx.x;          // 2 * 2^20 float4 granules
    const float* src; unsigned short* dst; int t; int swz;
    if (idx < (1 << 20)) { src = q; dst = qb; t = idx; swz = 0; }
    else                 { src = k; dst = kb; t = idx - (1 << 20); swz = 1; }
    int e = t << 2;
    int d = e & 63;
    int h = (e >> 6) & 15;
    int l = (e >> 10) & (LSEQ - 1);
    int n = e >> 21;
    float4 vv = reinterpret_cast<const float4*>(src)[t];
    int dd = d;
    if (swz) dd = ((((d >> 3) ^ (l & 7)) << 3) | (d & 7));
    else { vv.x *= QSCALE; vv.y *= QSCALE; vv.z *= QSCALE; vv.w *= QSCALE; }
    ushort4v o;
    o.x = f2bf(vv.x); o.y = f2bf(vv.y); o.z = f2bf(vv.z); o.w = f2bf(vv.w);
    size_t oi = (((size_t)n * NHEADS + h) * LSEQ + l) * HDIM + dd;
    *reinterpret_cast<ushort4v*>(dst + oi) = o;
  } else if (b < 9216) {
    int t = (b - 8192) * 256 + threadIdx.x;   // 2^18 float4 granules
    float4 vv = reinterpret_cast<const float4*>(w)[t];
    ushort4v o;
    o.x = f2bf(vv.x); o.y = f2bf(vv.y); o.z = f2bf(vv.z); o.w = f2bf(vv.w);
    reinterpret_cast<ushort4v*>(wb)[t] = o;
  } else if (b < 13312) {
    int idx = (b - 9216) * 256 + threadIdx.x; // 1M threads, 8 ints each
    const int* mp = mask + (size_t)idx * 8;
    int4 m0 = *reinterpret_cast<const int4*>(mp);
    int4 m1 = *reinterpret_cast<const int4*>(mp + 4);
    unsigned int bb = (m0.x ? 1u : 0u) | (m0.y ? 2u : 0u) | (m0.z ? 4u : 0u) |
                      (m0.w ? 8u : 0u) | (m1.x ? 16u : 0u) | (m1.y ? 32u : 0u) |
                      (m1.z ? 64u : 0u) | (m1.w ? 128u : 0u);
    mb8[idx] = (unsigned char)bb;
  } else {
    // V -> VT chunks [n][h][kc][d][slot32]; slot order = PV B-frag order:
    // slot s (g=s>>3, j=s&7): kp = (j<4) ? 4g+j : 16+4g+(j-4)
    // 16B-granule bank swizzle: c' = c ^ ((d>>1)&3)
    int b2 = b - 13312;              // n*16*64 + h*64 + kc
    int kc = b2 & 63;
    int h  = (b2 >> 6) & 15;
    int n  = b2 >> 10;
    int t  = threadIdx.x;
    int d    = t & 63;
    int sgrp = t >> 6;
    const float* src = v + (size_t)n * LSEQ * EMB + h * HDIM + d;
    ushort8v o;
#pragma unroll
    for (int j = 0; j < 8; ++j) {
      int kp = (j < 4) ? (4 * sgrp + j) : (16 + 4 * sgrp + (j - 4));
      float f = src[(size_t)(kc * 32 + kp) * EMB];
      o[j] = f2bf(f);
    }
    int cs = sgrp ^ ((d >> 1) & 3);
    size_t base = (((size_t)(n * NHEADS + h) * 64 + kc) * HDIM + d) * 32 + (cs << 3);
    *reinterpret_cast<ushort8v*>(vt + base) = o;
  }
}

// ---- Flash attention: LDS dbuf, KVBLK=64, 2 q-tiles (32 q-rows) per wave --
// Sequential per-tile softmax/PV keeps peak live VGPRs ~100 (no spill at cap 256).
__global__ __launch_bounds__(256, 2) void attn_kernel(
    const unsigned short* __restrict__ Kb, const unsigned short* __restrict__ Qb,
    const unsigned short* __restrict__ VT, const uint32_t* __restrict__ maskw,
    unsigned short* __restrict__ Op) {
  __shared__ unsigned short lds[2][8192];  // [buf][K (4096) | V (4096)] shorts

  int bid = blockIdx.x;
  bid = (bid & 7) * 64 + (bid >> 3);  // XCD swizzle (512 blocks, bijective)
  int qt = bid & 15;
  int h  = (bid >> 4) & 15;
  int n  = bid >> 8;
  int tid  = threadIdx.x;
  int wave = tid >> 6;
  int lane = tid & 63;
  int g  = lane >> 4;
  int qi = lane & 15;
  int qrow = qt * 128 + wave * 16 + qi;   // q-tile 0; q-tile 1 = qrow + 64

  const unsigned short* qptr = Qb + (((size_t)n * NHEADS + h) * LSEQ + qrow) * HDIM;
  bf16x8 bq0 = *reinterpret_cast<const bf16x8*>(qptr + g * 8);
  bf16x8 bq1 = *reinterpret_cast<const bf16x8*>(qptr + 32 + g * 8);
  bf16x8 bq2 = *reinterpret_cast<const bf16x8*>(qptr + 64 * HDIM + g * 8);
  bf16x8 bq3 = *reinterpret_cast<const bf16x8*>(qptr + 64 * HDIM + 32 + g * 8);

  const unsigned short* khead  = Kb + (((size_t)n * NHEADS + h) * LSEQ) * HDIM;
  const unsigned short* vthead = VT + ((size_t)(n * NHEADS + h) * 64) * (HDIM * 32);
  const uint32_t* mrow0 = maskw + ((size_t)n * LSEQ + qrow) * 64;
  const uint32_t* mrow1 = mrow0 + 64 * 64;

  // Loop-invariant LDS fragment offsets (shorts), swizzled
  int xk = qi & 7;
  int kA = qi * 64 + ((g ^ xk) << 3);
  int kB = qi * 64 + (((4 + g) ^ xk) << 3);
  int kC = kA + 1024;
  int kD = kB + 1024;
  int xv = (qi >> 1) & 3;
  int vA = qi * 32 + ((g ^ xv) << 3);
  int vB = vA + 512;
  int vC = vA + 1024;
  int vD = vA + 1536;

  f32x4 z = {0.f, 0.f, 0.f, 0.f};
  f32x4 acc0 = z, acc1 = z, acc2 = z, acc3 = z;      // q-tile 0, out^T[d][q]
  f32x4 acc4 = z, acc5 = z, acc6 = z, acc7 = z;      // q-tile 1
  float ssum0 = 0.f, ssum1 = 0.f;

#define STAGE(T, BUF) do {                                                     \
    const unsigned short* kg_ = khead  + (size_t)(T) * 4096 + tid * 8;         \
    const unsigned short* vg_ = vthead + (size_t)(T) * 4096 + tid * 8;         \
    __builtin_amdgcn_global_load_lds(                                          \
        (const __attribute__((address_space(1))) uint32_t*)kg_,                \
        (__attribute__((address_space(3))) uint32_t*)&lds[BUF][wave * 512],    \
        16, 0, 0);                                                             \
    __builtin_amdgcn_global_load_lds(                                          \
        (const __attribute__((address_space(1))) uint32_t*)(kg_ + 2048),       \
        (__attribute__((address_space(3))) uint32_t*)&lds[BUF][2048 + wave * 512], \
        16, 0, 0);                                                             \
    __builtin_amdgcn_global_load_lds(                                          \
        (const __attribute__((address_space(1))) uint32_t*)vg_,                \
        (__attribute__((address_space(3))) uint32_t*)&lds[BUF][4096 + wave * 512], \
        16, 0, 0);                                                             \
    __builtin_amdgcn_global_load_lds(                                          \
        (const __attribute__((address_space(1))) uint32_t*)(vg_ + 2048),       \
        (__attribute__((address_space(3))) uint32_t*)&lds[BUF][6144 + wave * 512], \
        16, 0, 0);                                                             \
  } while (0)

#define COMPUTE(BUF, CH, MA, MB) do {                                          \
    const unsigned short* lk_ = &lds[BUF][(CH) * 2048];                        \
    const unsigned short* lv_ = &lds[BUF][4096 + (CH) * 2048];                 \
    bf16x8 K0 = *(const bf16x8*)(lk_ + kA);                                    \
    bf16x8 K1 = *(const bf16x8*)(lk_ + kB);                                    \
    bf16x8 K2 = *(const bf16x8*)(lk_ + kC);                                    \
    bf16x8 K3 = *(const bf16x8*)(lk_ + kD);                                    \
    f32x4 e0 = z, e1 = z, f0 = z, f1 = z;                                      \
    e0 = mfma16(K0, bq0, e0); e0 = mfma16(K1, bq1, e0);                        \
    e1 = mfma16(K2, bq0, e1); e1 = mfma16(K3, bq1, e1);                        \
    f0 = mfma16(K0, bq2, f0); f0 = mfma16(K1, bq3, f0);                        \
    f1 = mfma16(K2, bq2, f1); f1 = mfma16(K3, bq3, f1);                        \
    bf16x8 V0 = *(const bf16x8*)(lv_ + vA);                                    \
    bf16x8 V1 = *(const bf16x8*)(lv_ + vB);                                    \
    bf16x8 V2 = *(const bf16x8*)(lv_ + vC);                                    \
    bf16x8 V3 = *(const bf16x8*)(lv_ + vD);                                    \
    {                                                                          \
      uint32_t m0_ = (MA) >> (4 * g);                                          \
      uint32_t m1_ = (MA) >> (16 + 4 * g);                                     \
      float p0 = mexp2(e0[0], m0_, 0);                                         \
      float p1 = mexp2(e0[1], m0_, 1);                                         \
      float p2 = mexp2(e0[2], m0_, 2);                                         \
      float p3 = mexp2(e0[3], m0_, 3);                                         \
      float p4 = mexp2(e1[0], m1_, 0);                                         \
      float p5 = mexp2(e1[1], m1_, 1);                                         \
      float p6 = mexp2(e1[2], m1_, 2);                                         \
      float p7 = mexp2(e1[3], m1_, 3);                                         \
      ssum0 += ((p0 + p1) + (p2 + p3)) + ((p4 + p5) + (p6 + p7));              \
      union { uint32_t u[4]; bf16x8 v; } pf;                                   \
      asm("v_cvt_pk_bf16_f32 %0, %1, %2" : "=v"(pf.u[0]) : "v"(p0), "v"(p1));  \
      asm("v_cvt_pk_bf16_f32 %0, %1, %2" : "=v"(pf.u[1]) : "v"(p2), "v"(p3));  \
      asm("v_cvt_pk_bf16_f32 %0, %1, %2" : "=v"(pf.u[2]) : "v"(p4), "v"(p5));  \
      asm("v_cvt_pk_bf16_f32 %0, %1, %2" : "=v"(pf.u[3]) : "v"(p6), "v"(p7));  \
      acc0 = mfma16(V0, pf.v, acc0);                                           \
      acc1 = mfma16(V1, pf.v, acc1);                                           \
      acc2 = mfma16(V2, pf.v, acc2);                                           \
      acc3 = mfma16(V3, pf.v, acc3);                                           \
    }                                                                          \
    {                                                                          \
      uint32_t m0_ = (MB) >> (4 * g);                                          \
      uint32_t m1_ = (MB) >> (16 + 4 * g);                                     \
      float r0 = mexp2(f0[0], m0_, 0);                                         \
      float r1 = mexp2(f0[1], m0_, 1);                                         \
      float r2 = mexp2(f0[2], m0_, 2);                                         \
      float r3 = mexp2(f0[3], m0_, 3);                                         \
      float r4 = mexp2(f1[0], m1_, 0);                                         \
      float r5 = mexp2(f1[1], m1_, 1);                                         \
      float r6 = mexp2(f1[2], m1_, 2);                                         \
      float r7 = mexp2(f1[3], m1_, 3);                                         \
      ssum1 += ((r0 + r1) + (r2 + r3)) + ((r4 + r5) + (r6 + r7));              \
      union { uint32_t u[4]; bf16x8 v; } pg;                                   \
      asm("v_cvt_pk_bf16_f32 %0, %1, %2" : "=v"(pg.u[0]) : "v"(r0), "v"(r1));  \
      asm("v_cvt_pk_bf16_f32 %0, %1, %2" : "=v"(pg.u[1]) : "v"(r2), "v"(r3));  \
      asm("v_cvt_pk_bf16_f32 %0, %1, %2" : "=v"(pg.u[2]) : "v"(r4), "v"(r5));  \
      asm("v_cvt_pk_bf16_f32 %0, %1, %2" : "=v"(pg.u[3]) : "v"(r6), "v"(r7));  \
      acc4 = mfma16(V0, pg.v, acc4);                                           \
      acc5 = mfma16(V1, pg.v, acc5);                                           \
      acc6 = mfma16(V2, pg.v, acc6);                                           \
      acc7 = mfma16(V3, pg.v, acc7);                                           \
    }                                                                          \
  } while (0)

  uint64_t ma0 = *(const uint64_t*)(mrow0);
  uint64_t mb0 = *(const uint64_t*)(mrow1);
  uint64_t ma1, mb1, ma2, mb2;
  STAGE(0, 0);
  __syncthreads();

  for (int t = 0; t < 32; t += 2) {
    int t1 = (t + 1) & 31;
    ma1 = *(const uint64_t*)(mrow0 + 2 * t1);
    mb1 = *(const uint64_t*)(mrow1 + 2 * t1);
    STAGE(t1, 1);
    COMPUTE(0, 0, (uint32_t)ma0, (uint32_t)mb0);
    COMPUTE(0, 1, (uint32_t)(ma0 >> 32), (uint32_t)(mb0 >> 32));
    __syncthreads();
    int t2 = (t + 2) & 31;
    ma2 = *(const uint64_t*)(mrow0 + 2 * t2);
    mb2 = *(const uint64_t*)(mrow1 + 2 * t2);
    STAGE(t2, 0);
    COMPUTE(1, 0, (uint32_t)ma1, (uint32_t)mb1);
    COMPUTE(1, 1, (uint32_t)(ma1 >> 32), (uint32_t)(mb1 >> 32));
    __syncthreads();
    ma0 = ma2; mb0 = mb2;
  }
#undef STAGE
#undef COMPUTE

  ssum0 += __shfl_xor(ssum0, 16, 64);
  ssum0 += __shfl_xor(ssum0, 32, 64);
  ssum1 += __shfl_xor(ssum1, 16, 64);
  ssum1 += __shfl_xor(ssum1, 32, 64);
  float inv0 = 1.0f / ssum0;
  float inv1 = 1.0f / ssum1;

  size_t ob0 = ((size_t)n * LSEQ + qrow) * EMB + h * HDIM;
  size_t ob1 = ob0 + (size_t)64 * EMB;
  ushort4v s0, s1, s2, s3, s4, s5, s6, s7;
#pragma unroll
  for (int r = 0; r < 4; ++r) {
    s0[r] = f2bf(acc0[r] * inv0);
    s1[r] = f2bf(acc1[r] * inv0);
    s2[r] = f2bf(acc2[r] * inv0);
    s3[r] = f2bf(acc3[r] * inv0);
    s4[r] = f2bf(acc4[r] * inv1);
    s5[r] = f2bf(acc5[r] * inv1);
    s6[r] = f2bf(acc6[r] * inv1);
    s7[r] = f2bf(acc7[r] * inv1);
  }
  *reinterpret_cast<ushort4v*>(Op + ob0 + 0  + 4 * g) = s0;
  *reinterpret_cast<ushort4v*>(Op + ob0 + 16 + 4 * g) = s1;
  *reinterpret_cast<ushort4v*>(Op + ob0 + 32 + 4 * g) = s2;
  *reinterpret_cast<ushort4v*>(Op + ob0 + 48 + 4 * g) = s3;
  *reinterpret_cast<ushort4v*>(Op + ob1 + 0  + 4 * g) = s4;
  *reinterpret_cast<ushort4v*>(Op + ob1 + 16 + 4 * g) = s5;
  *reinterpret_cast<ushort4v*>(Op + ob1 + 32 + 4 * g) = s6;
  *reinterpret_cast<ushort4v*>(Op + ob1 + 48 + 4 * g) = s7;
}

// ---- Projection: 128x64 block tile, LDS dbuf, out = A @ Wo^T + bo (fp32) --
__global__ __launch_bounds__(256, 2) void proj_kernel(
    const unsigned short* __restrict__ A, const unsigned short* __restrict__ B,
    const float* __restrict__ bo, float* __restrict__ out) {
  __shared__ unsigned short plds[2][6144];  // [buf][A: 0..4096 | B: 4096..6144]

  int bid = blockIdx.x;
  bid = (bid & 7) * 64 + (bid >> 3);  // XCD swizzle (512 blocks)
  int mb0 = (bid >> 4) * 128;
  int nb0 = (bid & 15) * 64;
  int tid  = threadIdx.x;
  int wave = tid >> 6;
  int lane = tid & 63;
  int g  = lane >> 4;
  int qi = lane & 15;
  int wm = wave >> 1, wn = wave & 1;

  // staging source (inverse-swizzled global read -> linear LDS dest)
  int srow = tid >> 2;
  int scol = (((tid & 3) ^ ((tid >> 3) & 3)) << 3);
  const unsigned short* aS0 = A + (size_t)(mb0 + srow) * EMB + scol;
  const unsigned short* aS1 = aS0 + (size_t)64 * EMB;
  const unsigned short* bS  = B + (size_t)(nb0 + srow) * EMB + scol;

  // swizzled ds_read offsets (shorts)
  int xa = (qi >> 1) & 3;
  int gof = ((g ^ xa) << 3);
  int aof0 = (wm * 64 + qi) * 32 + gof;
  int aof1 = aof0 + 16 * 32;
  int aof2 = aof0 + 32 * 32;
  int aof3 = aof0 + 48 * 32;
  int bof0 = (wn * 32 + qi) * 32 + gof;
  int bof1 = bof0 + 16 * 32;

  f32x4 z = {0.f, 0.f, 0.f, 0.f};
  f32x4 acc00 = z, acc01 = z, acc10 = z, acc11 = z;
  f32x4 acc20 = z, acc21 = z, acc30 = z, acc31 = z;

#define PSTAGE(KT, BUF) do {                                                   \
    __builtin_amdgcn_global_load_lds(                                          \
        (const __attribute__((address_space(1))) uint32_t*)(aS0 + (KT) * 32),  \
        (__attribute__((address_space(3))) uint32_t*)&plds[BUF][wave * 512],   \
        16, 0, 0);                                                             \
    __builtin_amdgcn_global_load_lds(                                          \
        (const __attribute__((address_space(1))) uint32_t*)(aS1 + (KT) * 32),  \
        (__attribute__((address_space(3))) uint32_t*)&plds[BUF][2048 + wave * 512], \
        16, 0, 0);                                                             \
    __builtin_amdgcn_global_load_lds(                                          \
        (const __attribute__((address_space(1))) uint32_t*)(bS + (KT) * 32),   \
        (__attribute__((address_space(3))) uint32_t*)&plds[BUF][4096 + wave * 512], \
        16, 0, 0);                                                             \
  } while (0)

#define PCOMPUTE(BUF) do {                                                     \
    const unsigned short* la_ = &plds[BUF][0];                                 \
    const unsigned short* lb_ = &plds[BUF][4096];                              \
    bf16x8 a0 = *(const bf16x8*)(la_ + aof0);                                  \
    bf16x8 a1 = *(const bf16x8*)(la_ + aof1);                                  \
    bf16x8 a2 = *(const bf16x8*)(la_ + aof2);                                  \
    bf16x8 a3 = *(const bf16x8*)(la_ + aof3);                                  \
    bf16x8 b0 = *(const bf16x8*)(lb_ + bof0);                                  \
    bf16x8 b1 = *(const bf16x8*)(lb_ + bof1);                                  \
    acc00 = mfma16(a0, b0, acc00); acc01 = mfma16(a0, b1, acc01);              \
    acc10 = mfma16(a1, b0, acc10); acc11 = mfma16(a1, b1, acc11);              \
    acc20 = mfma16(a2, b0, acc20); acc21 = mfma16(a2, b1, acc21);              \
    acc30 = mfma16(a3, b0, acc30); acc31 = mfma16(a3, b1, acc31);              \
  } while (0)

  PSTAGE(0, 0);
  __syncthreads();
  for (int kt = 0; kt < 32; kt += 2) {
    PSTAGE(kt + 1, 1);
    PCOMPUTE(0);
    __syncthreads();
    PSTAGE((kt + 2) & 31, 0);
    PCOMPUTE(1);
    __syncthreads();
  }
#undef PSTAGE
#undef PCOMPUTE

  int orow = mb0 + wm * 64 + 4 * g;
  int col0 = nb0 + wn * 32 + qi;
  float bia0 = bo[col0];
  float bia1 = bo[col0 + 16];
#define PSTORE(ACC0, ACC1, M) do {                                             \
    _Pragma("unroll")                                                          \
    for (int r = 0; r < 4; ++r) {                                              \
      size_t rw = (size_t)(orow + (M) * 16 + r) * EMB;                         \
      out[rw + col0]      = ACC0[r] + bia0;                                    \
      out[rw + col0 + 16] = ACC1[r] + bia1;                                    \
    }                                                                          \
  } while (0)
  PSTORE(acc00, acc01, 0);
  PSTORE(acc10, acc11, 1);
  PSTORE(acc20, acc21, 2);
  PSTORE(acc30, acc31, 3);
#undef PSTORE
}

extern "C" void kernel_launch(void* const* d_in, const int* in_sizes, int n_in,
                              void* d_out, int out_size, void* d_ws, size_t ws_size,
                              hipStream_t stream) {
  const float* Vf   = (const float*)d_in[0];
  const float* Kf   = (const float*)d_in[1];
  const float* Qf   = (const float*)d_in[2];
  const int*   Mask = (const int*)d_in[3];
  const float* Wo   = (const float*)d_in[4];
  const float* Bo   = (const float*)d_in[5];
  float* out = (float*)d_out;

  char* ws = (char*)d_ws;
  // ws layout (bytes): Qb 8MB | Kb 8MB | VT 8MB | Wob 2MB | Opb 8MB | Mb 1MB
  unsigned short* Qb  = (unsigned short*)(ws);
  unsigned short* Kb  = (unsigned short*)(ws + (size_t)8  * 1024 * 1024);
  unsigned short* VTb = (unsigned short*)(ws + (size_t)16 * 1024 * 1024);
  unsigned short* Wob = (unsigned short*)(ws + (size_t)24 * 1024 * 1024);
  unsigned short* Opb = (unsigned short*)(ws + (size_t)26 * 1024 * 1024);
  unsigned char*  Mb  = (unsigned char*)(ws + (size_t)34 * 1024 * 1024);

  prep_kernel<<<15360, 256, 0, stream>>>(Qf, Kf, Wo, Mask, Vf, Qb, Kb, Wob, Mb, VTb);
  attn_kernel<<<512, 256, 0, stream>>>(Kb, Qb, VTb, (const uint32_t*)Mb, Opb);
  proj_kernel<<<512, 256, 0, stream>>>(Opb, Wob, Bo, out);
}

// Round 8
// 83.826 us; speedup vs baseline: 3.8385x; 1.0675x over previous
//
#include <hip/hip_runtime.h>
#include <hip/hip_bf16.h>
#include <stdint.h>

#define LSEQ 2048
#define NBATCH 2
#define NHEADS 16
#define HDIM 64
#define EMB 1024

typedef __bf16 bf16x8 __attribute__((ext_vector_type(8)));
typedef float f32x4 __attribute__((ext_vector_type(4)));
typedef unsigned short ushort4v __attribute__((ext_vector_type(4)));
typedef unsigned short ushort8v __attribute__((ext_vector_type(8)));

// Q is prescaled by c = log2e/32 so QK^T MFMA yields log2-domain logits
// directly; the fixed-max bias 2^(-96c) cancels in acc/ssum (p <= ~4).
#define QSCALE (1.44269504088896f / 32.0f)

static __device__ __forceinline__ unsigned short f2bf(float f) {
  union { float f; uint32_t u; } v; v.f = f;
  uint32_t u = v.u;
  u += 0x7fffu + ((u >> 16) & 1u);   // RNE
  return (unsigned short)(u >> 16);
}

static __device__ __forceinline__ f32x4 mfma16(bf16x8 a, bf16x8 b, f32x4 c) {
  return __builtin_amdgcn_mfma_f32_16x16x32_bf16(a, b, c, 0, 0, 0);
}

// masked exp2: bit b of m selects exp2(e) or 0.0 (2 VALU: sbfe + and)
static __device__ __forceinline__ float mexp2(float e, uint32_t m, int b) {
  uint32_t keep = (uint32_t)__builtin_amdgcn_sbfe((int)m, b, 1);
  return __uint_as_float(__float_as_uint(__builtin_amdgcn_exp2f(e)) & keep);
}

// ---- prep: Q(scaled),K(swizzled) convert, Wo convert, mask->bytes, VT ----
// blocks [0,8192): QK. [8192,9216): Wo. [9216,13312): mask. [13312,15360): VT.
__global__ __launch_bounds__(256) void prep_kernel(
    const float* __restrict__ q, const float* __restrict__ k,
    const float* __restrict__ w, const int* __restrict__ mask,
    const float* __restrict__ v,
    unsigned short* __restrict__ qb, unsigned short* __restrict__ kb,
    unsigned short* __restrict__ wb, unsigned char* __restrict__ mb8,
    unsigned short* __restrict__ vt) {
  int b = blockIdx.x;
  if (b < 8192) {
    int idx = b * 256 + threadIdx.x;          // 2 * 2^20 float4 granules
    const float* src; unsigned short* dst; int t; int swz;
    if (idx < (1 << 20)) { src = q; dst = qb; t = idx; swz = 0; }
    else                 { src = k; dst = kb; t = idx - (1 << 20); swz = 1; }
    int e = t << 2;
    int d = e & 63;
    int h = (e >> 6) & 15;
    int l = (e >> 10) & (LSEQ - 1);
    int n = e >> 21;
    float4 vv = reinterpret_cast<const float4*>(src)[t];
    int dd = d;
    if (swz) dd = ((((d >> 3) ^ (l & 7)) << 3) | (d & 7));
    else { vv.x *= QSCALE; vv.y *= QSCALE; vv.z *= QSCALE; vv.w *= QSCALE; }
    ushort4v o;
    o.x = f2bf(vv.x); o.y = f2bf(vv.y); o.z = f2bf(vv.z); o.w = f2bf(vv.w);
    size_t oi = (((size_t)n * NHEADS + h) * LSEQ + l) * HDIM + dd;
    *reinterpret_cast<ushort4v*>(dst + oi) = o;
  } else if (b < 9216) {
    int t = (b - 8192) * 256 + threadIdx.x;   // 2^18 float4 granules
    float4 vv = reinterpret_cast<const float4*>(w)[t];
    ushort4v o;
    o.x = f2bf(vv.x); o.y = f2bf(vv.y); o.z = f2bf(vv.z); o.w = f2bf(vv.w);
    reinterpret_cast<ushort4v*>(wb)[t] = o;
  } else if (b < 13312) {
    int idx = (b - 9216) * 256 + threadIdx.x; // 1M threads, 8 ints each
    const int* mp = mask + (size_t)idx * 8;
    int4 m0 = *reinterpret_cast<const int4*>(mp);
    int4 m1 = *reinterpret_cast<const int4*>(mp + 4);
    unsigned int bb = (m0.x ? 1u : 0u) | (m0.y ? 2u : 0u) | (m0.z ? 4u : 0u) |
                      (m0.w ? 8u : 0u) | (m1.x ? 16u : 0u) | (m1.y ? 32u : 0u) |
                      (m1.z ? 64u : 0u) | (m1.w ? 128u : 0u);
    mb8[idx] = (unsigned char)bb;
  } else {
    // V -> VT chunks [n][h][kc][d][slot32]; slot order = PV B-frag order:
    // slot s (g=s>>3, j=s&7): kp = (j<4) ? 4g+j : 16+4g+(j-4)
    // 16B-granule bank swizzle: c' = c ^ ((d>>1)&3)
    int b2 = b - 13312;              // n*16*64 + h*64 + kc
    int kc = b2 & 63;
    int h  = (b2 >> 6) & 15;
    int n  = b2 >> 10;
    int t  = threadIdx.x;
    int d    = t & 63;
    int sgrp = t >> 6;
    const float* src = v + (size_t)n * LSEQ * EMB + h * HDIM + d;
    ushort8v o;
#pragma unroll
    for (int j = 0; j < 8; ++j) {
      int kp = (j < 4) ? (4 * sgrp + j) : (16 + 4 * sgrp + (j - 4));
      float f = src[(size_t)(kc * 32 + kp) * EMB];
      o[j] = f2bf(f);
    }
    int cs = sgrp ^ ((d >> 1) & 3);
    size_t base = (((size_t)(n * NHEADS + h) * 64 + kc) * HDIM + d) * 32 + (cs << 3);
    *reinterpret_cast<ushort8v*>(vt + base) = o;
  }
}

// ---- Flash attention: LDS dbuf, KVBLK=128, 2 q-tiles/wave, MFMA-ssum -----
__global__ __launch_bounds__(256, 2) void attn_kernel(
    const unsigned short* __restrict__ Kb, const unsigned short* __restrict__ Qb,
    const unsigned short* __restrict__ VT, const uint32_t* __restrict__ maskw,
    unsigned short* __restrict__ Op) {
  __shared__ unsigned short lds[2][16384];  // [buf][K:0..8191 | V:8192..16383]

  int bid = blockIdx.x;
  bid = (bid & 7) * 64 + (bid >> 3);  // XCD swizzle (512 blocks, bijective)
  int qt = bid & 15;
  int h  = (bid >> 4) & 15;
  int n  = bid >> 8;
  int tid  = threadIdx.x;
  int wave = tid >> 6;
  int lane = tid & 63;
  int g  = lane >> 4;
  int qi = lane & 15;
  int qrow = qt * 128 + wave * 16 + qi;   // q-tile 0; q-tile 1 = qrow + 64

  const unsigned short* qptr = Qb + (((size_t)n * NHEADS + h) * LSEQ + qrow) * HDIM;
  bf16x8 bq0 = *reinterpret_cast<const bf16x8*>(qptr + g * 8);
  bf16x8 bq1 = *reinterpret_cast<const bf16x8*>(qptr + 32 + g * 8);
  bf16x8 bq2 = *reinterpret_cast<const bf16x8*>(qptr + 64 * HDIM + g * 8);
  bf16x8 bq3 = *reinterpret_cast<const bf16x8*>(qptr + 64 * HDIM + 32 + g * 8);

  const unsigned short* khead  = Kb + (((size_t)n * NHEADS + h) * LSEQ) * HDIM;
  const unsigned short* vthead = VT + ((size_t)(n * NHEADS + h) * 64) * (HDIM * 32);
  const uint32_t* mrow0 = maskw + ((size_t)n * LSEQ + qrow) * 64;
  const uint32_t* mrow1 = mrow0 + 64 * 64;

  // Loop-invariant LDS fragment offsets (shorts), swizzled
  int xk = qi & 7;
  int kA = qi * 64 + ((g ^ xk) << 3);
  int kB = qi * 64 + (((4 + g) ^ xk) << 3);
  int kC = kA + 1024;
  int kD = kB + 1024;
  int xv = (qi >> 1) & 3;
  int vA = qi * 32 + ((g ^ xv) << 3);
  int vB = vA + 512;
  int vC = vA + 1024;
  int vD = vA + 1536;

  // all-ones A fragment: D = ones(16x32) @ P sums P over full K dim ->
  // every acc row = per-q-column running sum (replaces VALU ssum + shfl).
  union { uint32_t u[4]; bf16x8 v; } ones;
  ones.u[0] = 0x3F803F80u; ones.u[1] = 0x3F803F80u;
  ones.u[2] = 0x3F803F80u; ones.u[3] = 0x3F803F80u;

  f32x4 z = {0.f, 0.f, 0.f, 0.f};
  f32x4 acc0 = z, acc1 = z, acc2 = z, acc3 = z;      // q-tile 0, out^T[d][q]
  f32x4 acc4 = z, acc5 = z, acc6 = z, acc7 = z;      // q-tile 1
  f32x4 sacc0 = z, sacc1 = z;                        // softmax denominators

#define STAGE(T, BUF) do {                                                     \
    const unsigned short* kg_ = khead  + (size_t)(T) * 8192 + tid * 8;         \
    const unsigned short* vg_ = vthead + (size_t)(T) * 8192 + tid * 8;         \
    _Pragma("unroll")                                                          \
    for (int j_ = 0; j_ < 4; ++j_) {                                           \
      __builtin_amdgcn_global_load_lds(                                        \
          (const __attribute__((address_space(1))) uint32_t*)(kg_ + j_ * 2048),\
          (__attribute__((address_space(3))) uint32_t*)                        \
              &lds[BUF][j_ * 2048 + wave * 512],                               \
          16, 0, 0);                                                           \
      __builtin_amdgcn_global_load_lds(                                        \
          (const __attribute__((address_space(1))) uint32_t*)(vg_ + j_ * 2048),\
          (__attribute__((address_space(3))) uint32_t*)                        \
              &lds[BUF][8192 + j_ * 2048 + wave * 512],                        \
          16, 0, 0);                                                           \
    }                                                                          \
  } while (0)

#define COMPUTE(BUF, CH, MA, MB) do {                                          \
    const unsigned short* lk_ = &lds[BUF][(CH) * 2048];                        \
    const unsigned short* lv_ = &lds[BUF][8192 + (CH) * 2048];                 \
    bf16x8 K0 = *(const bf16x8*)(lk_ + kA);                                    \
    bf16x8 K1 = *(const bf16x8*)(lk_ + kB);                                    \
    bf16x8 K2 = *(const bf16x8*)(lk_ + kC);                                    \
    bf16x8 K3 = *(const bf16x8*)(lk_ + kD);                                    \
    f32x4 e0 = z, e1 = z, f0 = z, f1 = z;                                      \
    e0 = mfma16(K0, bq0, e0); e0 = mfma16(K1, bq1, e0);                        \
    e1 = mfma16(K2, bq0, e1); e1 = mfma16(K3, bq1, e1);                        \
    f0 = mfma16(K0, bq2, f0); f0 = mfma16(K1, bq3, f0);                        \
    f1 = mfma16(K2, bq2, f1); f1 = mfma16(K3, bq3, f1);                        \
    bf16x8 V0 = *(const bf16x8*)(lv_ + vA);                                    \
    bf16x8 V1 = *(const bf16x8*)(lv_ + vB);                                    \
    bf16x8 V2 = *(const bf16x8*)(lv_ + vC);                                    \
    bf16x8 V3 = *(const bf16x8*)(lv_ + vD);                                    \
    {                                                                          \
      uint32_t m0_ = (MA) >> (4 * g);                                          \
      uint32_t m1_ = (MA) >> (16 + 4 * g);                                     \
      float p0 = mexp2(e0[0], m0_, 0);                                         \
      float p1 = mexp2(e0[1], m0_, 1);                                         \
      float p2 = mexp2(e0[2], m0_, 2);                                         \
      float p3 = mexp2(e0[3], m0_, 3);                                         \
      float p4 = mexp2(e1[0], m1_, 0);                                         \
      float p5 = mexp2(e1[1], m1_, 1);                                         \
      float p6 = mexp2(e1[2], m1_, 2);                                         \
      float p7 = mexp2(e1[3], m1_, 3);                                         \
      union { uint32_t u[4]; bf16x8 v; } pf;                                   \
      asm("v_cvt_pk_bf16_f32 %0, %1, %2" : "=v"(pf.u[0]) : "v"(p0), "v"(p1));  \
      asm("v_cvt_pk_bf16_f32 %0, %1, %2" : "=v"(pf.u[1]) : "v"(p2), "v"(p3));  \
      asm("v_cvt_pk_bf16_f32 %0, %1, %2" : "=v"(pf.u[2]) : "v"(p4), "v"(p5));  \
      asm("v_cvt_pk_bf16_f32 %0, %1, %2" : "=v"(pf.u[3]) : "v"(p6), "v"(p7));  \
      acc0 = mfma16(V0, pf.v, acc0);                                           \
      acc1 = mfma16(V1, pf.v, acc1);                                           \
      acc2 = mfma16(V2, pf.v, acc2);                                           \
      acc3 = mfma16(V3, pf.v, acc3);                                           \
      sacc0 = mfma16(ones.v, pf.v, sacc0);                                     \
    }                                                                          \
    {                                                                          \
      uint32_t m0_ = (MB) >> (4 * g);                                          \
      uint32_t m1_ = (MB) >> (16 + 4 * g);                                     \
      float r0 = mexp2(f0[0], m0_, 0);                                         \
      float r1 = mexp2(f0[1], m0_, 1);                                         \
      float r2 = mexp2(f0[2], m0_, 2);                                         \
      float r3 = mexp2(f0[3], m0_, 3);                                         \
      float r4 = mexp2(f1[0], m1_, 0);                                         \
      float r5 = mexp2(f1[1], m1_, 1);                                         \
      float r6 = mexp2(f1[2], m1_, 2);                                         \
      float r7 = mexp2(f1[3], m1_, 3);                                         \
      union { uint32_t u[4]; bf16x8 v; } pg;                                   \
      asm("v_cvt_pk_bf16_f32 %0, %1, %2" : "=v"(pg.u[0]) : "v"(r0), "v"(r1));  \
      asm("v_cvt_pk_bf16_f32 %0, %1, %2" : "=v"(pg.u[1]) : "v"(r2), "v"(r3));  \
      asm("v_cvt_pk_bf16_f32 %0, %1, %2" : "=v"(pg.u[2]) : "v"(r4), "v"(r5));  \
      asm("v_cvt_pk_bf16_f32 %0, %1, %2" : "=v"(pg.u[3]) : "v"(r6), "v"(r7));  \
      acc4 = mfma16(V0, pg.v, acc4);                                           \
      acc5 = mfma16(V1, pg.v, acc5);                                           \
      acc6 = mfma16(V2, pg.v, acc6);                                           \
      acc7 = mfma16(V3, pg.v, acc7);                                           \
      sacc1 = mfma16(ones.v, pg.v, sacc1);                                     \
    }                                                                          \
  } while (0)

  uint4 ma0 = *(const uint4*)(mrow0);
  uint4 mb0 = *(const uint4*)(mrow1);
  uint4 ma1, mb1, ma2, mb2;
  STAGE(0, 0);
  __syncthreads();

  for (int t = 0; t < 16; t += 2) {
    int t1 = (t + 1) & 15;
    ma1 = *(const uint4*)(mrow0 + 4 * t1);
    mb1 = *(const uint4*)(mrow1 + 4 * t1);
    STAGE(t1, 1);
    COMPUTE(0, 0, ma0.x, mb0.x);
    COMPUTE(0, 1, ma0.y, mb0.y);
    COMPUTE(0, 2, ma0.z, mb0.z);
    COMPUTE(0, 3, ma0.w, mb0.w);
    __syncthreads();
    int t2 = (t + 2) & 15;
    ma2 = *(const uint4*)(mrow0 + 4 * t2);
    mb2 = *(const uint4*)(mrow1 + 4 * t2);
    STAGE(t2, 0);
    COMPUTE(1, 0, ma1.x, mb1.x);
    COMPUTE(1, 1, ma1.y, mb1.y);
    COMPUTE(1, 2, ma1.z, mb1.z);
    COMPUTE(1, 3, ma1.w, mb1.w);
    __syncthreads();
    ma0 = ma2; mb0 = mb2;
  }
#undef STAGE
#undef COMPUTE

  float inv0 = 1.0f / sacc0[0];
  float inv1 = 1.0f / sacc1[0];

  size_t ob0 = ((size_t)n * LSEQ + qrow) * EMB + h * HDIM;
  size_t ob1 = ob0 + (size_t)64 * EMB;
  ushort4v s0, s1, s2, s3, s4, s5, s6, s7;
#pragma unroll
  for (int r = 0; r < 4; ++r) {
    s0[r] = f2bf(acc0[r] * inv0);
    s1[r] = f2bf(acc1[r] * inv0);
    s2[r] = f2bf(acc2[r] * inv0);
    s3[r] = f2bf(acc3[r] * inv0);
    s4[r] = f2bf(acc4[r] * inv1);
    s5[r] = f2bf(acc5[r] * inv1);
    s6[r] = f2bf(acc6[r] * inv1);
    s7[r] = f2bf(acc7[r] * inv1);
  }
  *reinterpret_cast<ushort4v*>(Op + ob0 + 0  + 4 * g) = s0;
  *reinterpret_cast<ushort4v*>(Op + ob0 + 16 + 4 * g) = s1;
  *reinterpret_cast<ushort4v*>(Op + ob0 + 32 + 4 * g) = s2;
  *reinterpret_cast<ushort4v*>(Op + ob0 + 48 + 4 * g) = s3;
  *reinterpret_cast<ushort4v*>(Op + ob1 + 0  + 4 * g) = s4;
  *reinterpret_cast<ushort4v*>(Op + ob1 + 16 + 4 * g) = s5;
  *reinterpret_cast<ushort4v*>(Op + ob1 + 32 + 4 * g) = s6;
  *reinterpret_cast<ushort4v*>(Op + ob1 + 48 + 4 * g) = s7;
}

// ---- Projection: 128x64 block tile, LDS dbuf, out = A @ Wo^T + bo (fp32) --
__global__ __launch_bounds__(256, 2) void proj_kernel(
    const unsigned short* __restrict__ A, const unsigned short* __restrict__ B,
    const float* __restrict__ bo, float* __restrict__ out) {
  __shared__ unsigned short plds[2][6144];  // [buf][A: 0..4096 | B: 4096..6144]

  int bid = blockIdx.x;
  bid = (bid & 7) * 64 + (bid >> 3);  // XCD swizzle (512 blocks)
  int mb0 = (bid >> 4) * 128;
  int nb0 = (bid & 15) * 64;
  int tid  = threadIdx.x;
  int wave = tid >> 6;
  int lane = tid & 63;
  int g  = lane >> 4;
  int qi = lane & 15;
  int wm = wave >> 1, wn = wave & 1;

  // staging source (inverse-swizzled global read -> linear LDS dest)
  int srow = tid >> 2;
  int scol = (((tid & 3) ^ ((tid >> 3) & 3)) << 3);
  const unsigned short* aS0 = A + (size_t)(mb0 + srow) * EMB + scol;
  const unsigned short* aS1 = aS0 + (size_t)64 * EMB;
  const unsigned short* bS  = B + (size_t)(nb0 + srow) * EMB + scol;

  // swizzled ds_read offsets (shorts)
  int xa = (qi >> 1) & 3;
  int gof = ((g ^ xa) << 3);
  int aof0 = (wm * 64 + qi) * 32 + gof;
  int aof1 = aof0 + 16 * 32;
  int aof2 = aof0 + 32 * 32;
  int aof3 = aof0 + 48 * 32;
  int bof0 = (wn * 32 + qi) * 32 + gof;
  int bof1 = bof0 + 16 * 32;

  f32x4 z = {0.f, 0.f, 0.f, 0.f};
  f32x4 acc00 = z, acc01 = z, acc10 = z, acc11 = z;
  f32x4 acc20 = z, acc21 = z, acc30 = z, acc31 = z;

#define PSTAGE(KT, BUF) do {                                                   \
    __builtin_amdgcn_global_load_lds(                                          \
        (const __attribute__((address_space(1))) uint32_t*)(aS0 + (KT) * 32),  \
        (__attribute__((address_space(3))) uint32_t*)&plds[BUF][wave * 512],   \
        16, 0, 0);                                                             \
    __builtin_amdgcn_global_load_lds(                                          \
        (const __attribute__((address_space(1))) uint32_t*)(aS1 + (KT) * 32),  \
        (__attribute__((address_space(3))) uint32_t*)&plds[BUF][2048 + wave * 512], \
        16, 0, 0);                                                             \
    __builtin_amdgcn_global_load_lds(                                          \
        (const __attribute__((address_space(1))) uint32_t*)(bS + (KT) * 32),   \
        (__attribute__((address_space(3))) uint32_t*)&plds[BUF][4096 + wave * 512], \
        16, 0, 0);                                                             \
  } while (0)

#define PCOMPUTE(BUF) do {                                                     \
    const unsigned short* la_ = &plds[BUF][0];                                 \
    const unsigned short* lb_ = &plds[BUF][4096];                              \
    bf16x8 a0 = *(const bf16x8*)(la_ + aof0);                                  \
    bf16x8 a1 = *(const bf16x8*)(la_ + aof1);                                  \
    bf16x8 a2 = *(const bf16x8*)(la_ + aof2);                                  \
    bf16x8 a3 = *(const bf16x8*)(la_ + aof3);                                  \
    bf16x8 b0 = *(const bf16x8*)(lb_ + bof0);                                  \
    bf16x8 b1 = *(const bf16x8*)(lb_ + bof1);                                  \
    acc00 = mfma16(a0, b0, acc00); acc01 = mfma16(a0, b1, acc01);              \
    acc10 = mfma16(a1, b0, acc10); acc11 = mfma16(a1, b1, acc11);              \
    acc20 = mfma16(a2, b0, acc20); acc21 = mfma16(a2, b1, acc21);              \
    acc30 = mfma16(a3, b0, acc30); acc31 = mfma16(a3, b1, acc31);              \
  } while (0)

  PSTAGE(0, 0);
  __syncthreads();
  for (int kt = 0; kt < 32; kt += 2) {
    PSTAGE(kt + 1, 1);
    PCOMPUTE(0);
    __syncthreads();
    PSTAGE((kt + 2) & 31, 0);
    PCOMPUTE(1);
    __syncthreads();
  }
#undef PSTAGE
#undef PCOMPUTE

  int orow = mb0 + wm * 64 + 4 * g;
  int col0 = nb0 + wn * 32 + qi;
  float bia0 = bo[col0];
  float bia1 = bo[col0 + 16];
#define PSTORE(ACC0, ACC1, M) do {                                             \
    _Pragma("unroll")                                                          \
    for (int r = 0; r < 4; ++r) {                                              \
      size_t rw = (size_t)(orow + (M) * 16 + r) * EMB;                         \
      out[rw + col0]      = ACC0[r] + bia0;                                    \
      out[rw + col0 + 16] = ACC1[r] + bia1;                                    \
    }                                                                          \
  } while (0)
  PSTORE(acc00, acc01, 0);
  PSTORE(acc10, acc11, 1);
  PSTORE(acc20, acc21, 2);
  PSTORE(acc30, acc31, 3);
#undef PSTORE
}

extern "C" void kernel_launch(void* const* d_in, const int* in_sizes, int n_in,
                              void* d_out, int out_size, void* d_ws, size_t ws_size,
                              hipStream_t stream) {
  const float* Vf   = (const float*)d_in[0];
  const float* Kf   = (const float*)d_in[1];
  const float* Qf   = (const float*)d_in[2];
  const int*   Mask = (const int*)d_in[3];
  const float* Wo   = (const float*)d_in[4];
  const float* Bo   = (const float*)d_in[5];
  float* out = (float*)d_out;

  char* ws = (char*)d_ws;
  // ws layout (bytes): Qb 8MB | Kb 8MB | VT 8MB | Wob 2MB | Opb 8MB | Mb 1MB
  unsigned short* Qb  = (unsigned short*)(ws);
  unsigned short* Kb  = (unsigned short*)(ws + (size_t)8  * 1024 * 1024);
  unsigned short* VTb = (unsigned short*)(ws + (size_t)16 * 1024 * 1024);
  unsigned short* Wob = (unsigned short*)(ws + (size_t)24 * 1024 * 1024);
  unsigned short* Opb = (unsigned short*)(ws + (size_t)26 * 1024 * 1024);
  unsigned char*  Mb  = (unsigned char*)(ws + (size_t)34 * 1024 * 1024);

  prep_kernel<<<15360, 256, 0, stream>>>(Qf, Kf, Wo, Mask, Vf, Qb, Kb, Wob, Mb, VTb);
  attn_kernel<<<512, 256, 0, stream>>>(Kb, Qb, VTb, (const uint32_t*)Mb, Opb);
  proj_kernel<<<512, 256, 0, stream>>>(Opb, Wob, Bo, out);
}